// Round 1
// baseline (4059.468 us; speedup 1.0000x reference)
//
#include <hip/hip_runtime.h>
#include <cstddef>

#define LN_EPS 1e-5f

constexpr int BM = 64, BN = 64, BK = 16;

// C[M x Ncols] = act( A[M x K] @ op(B) + bias (+ A2 @ op(B2) + bias2) )
// TRANSB: B is [Ncols x K] row-major (torch Linear weight) -> use B^T
// else:   B is [K x Ncols] row-major
template<bool TRANSB, bool DUAL, int ACT>
__global__ __launch_bounds__(256)
void gemm_kernel(const float* __restrict__ A, const float* __restrict__ Bm,
                 const float* __restrict__ bias,
                 const float* __restrict__ A2, const float* __restrict__ B2,
                 const float* __restrict__ bias2,
                 float* __restrict__ C,
                 int M, int Ncols, int K,
                 long long sAb, long long sBb, long long sCb)
{
    // +4 pad keeps rows 16B-aligned (272B stride) so compute reads vectorize to ds_read_b128
    __shared__ float sA[BK][BM + 4];
    __shared__ float sB[BK][BN + 4];

    const int bn = blockIdx.x * BN;
    const int bm = blockIdx.y * BM;
    const long long z = blockIdx.z;

    const int t  = threadIdx.x;
    const int tx = t & 15, ty = t >> 4;

    float acc[4][4];
#pragma unroll
    for (int i = 0; i < 4; ++i)
#pragma unroll
        for (int j = 0; j < 4; ++j) acc[i][j] = 0.f;

#pragma unroll
    for (int phase = 0; phase < (DUAL ? 2 : 1); ++phase) {
        const float* Ap = (phase == 0 ? A : A2) + z * sAb;
        const float* Bp = (phase == 0 ? Bm : B2) + z * sBb;

        for (int k0 = 0; k0 < K; k0 += BK) {
            {   // A tile: 64 rows x 16 k, one float4 per thread
                int mm = t >> 2;
                int kq = (t & 3) << 2;
                const float4 av = *(const float4*)(Ap + (long long)(bm + mm) * K + k0 + kq);
                sA[kq + 0][mm] = av.x; sA[kq + 1][mm] = av.y;
                sA[kq + 2][mm] = av.z; sA[kq + 3][mm] = av.w;
            }
            if (TRANSB) {
                int nn = t >> 2;
                int kq = (t & 3) << 2;
                const float4 bv = *(const float4*)(Bp + (long long)(bn + nn) * K + k0 + kq);
                sB[kq + 0][nn] = bv.x; sB[kq + 1][nn] = bv.y;
                sB[kq + 2][nn] = bv.z; sB[kq + 3][nn] = bv.w;
            } else {
                int kk = t >> 4;
                int nq = (t & 15) << 2;
                const float4 bv = *(const float4*)(Bp + (long long)(k0 + kk) * Ncols + bn + nq);
                *(float4*)&sB[kk][nq] = bv;
            }
            __syncthreads();
#pragma unroll
            for (int k = 0; k < BK; ++k) {
                float a0 = sA[k][ty * 4 + 0], a1 = sA[k][ty * 4 + 1];
                float a2 = sA[k][ty * 4 + 2], a3 = sA[k][ty * 4 + 3];
                float b0 = sB[k][tx * 4 + 0], b1 = sB[k][tx * 4 + 1];
                float b2 = sB[k][tx * 4 + 2], b3 = sB[k][tx * 4 + 3];
                acc[0][0] += a0 * b0; acc[0][1] += a0 * b1; acc[0][2] += a0 * b2; acc[0][3] += a0 * b3;
                acc[1][0] += a1 * b0; acc[1][1] += a1 * b1; acc[1][2] += a1 * b2; acc[1][3] += a1 * b3;
                acc[2][0] += a2 * b0; acc[2][1] += a2 * b1; acc[2][2] += a2 * b2; acc[2][3] += a2 * b3;
                acc[3][0] += a3 * b0; acc[3][1] += a3 * b1; acc[3][2] += a3 * b2; acc[3][3] += a3 * b3;
            }
            __syncthreads();
        }
    }

    float* Cp = C + z * sCb;
#pragma unroll
    for (int i = 0; i < 4; ++i) {
        int row = bm + ty * 4 + i;
#pragma unroll
        for (int j = 0; j < 4; ++j) {
            int col = bn + tx * 4 + j;
            float v = acc[i][j];
            if (bias) v += bias[col];
            if (DUAL && bias2) v += bias2[col];
            if (ACT == 1) v = v > 0.f ? v : 0.f;
            Cp[(long long)row * Ncols + col] = v;
        }
    }
}

// init MLP (2->H->H->H) + LayerNorm of the (identical-per-node) init vector.
__global__ __launch_bounds__(128)
void init_kernel(const float* __restrict__ kk, const float* __restrict__ nn,
                 const float* __restrict__ w1, const float* __restrict__ b1,
                 const float* __restrict__ w2, const float* __restrict__ b2,
                 const float* __restrict__ w3, const float* __restrict__ b3,
                 const float* __restrict__ lng, const float* __restrict__ lnb,
                 float* __restrict__ init0, float* __restrict__ embed0, int H)
{
    int b = blockIdx.x, j = threadIdx.x;
    __shared__ float s1[128];
    __shared__ float s2[128];
    __shared__ float red[128];
    float kv = kk[b], nv = nn[b];
    float h1 = w1[j * 2 + 0] * kv + w1[j * 2 + 1] * nv + b1[j];
    h1 = h1 > 0.f ? h1 : 0.f;
    s1[j] = h1; __syncthreads();
    float h2 = b2[j];
    for (int q = 0; q < H; ++q) h2 += w2[j * H + q] * s1[q];
    h2 = h2 > 0.f ? h2 : 0.f;
    s2[j] = h2; __syncthreads();
    float o = b3[j];
    for (int q = 0; q < H; ++q) o += w3[j * H + q] * s2[q];
    init0[b * H + j] = o;

    red[j] = o; __syncthreads();
    for (int s = 64; s > 0; s >>= 1) { if (j < s) red[j] += red[j + s]; __syncthreads(); }
    float mu = red[0] / (float)H;
    __syncthreads();
    float d = o - mu;
    red[j] = d * d; __syncthreads();
    for (int s = 64; s > 0; s >>= 1) { if (j < s) red[j] += red[j + s]; __syncthreads(); }
    float var = red[0] / (float)H;
    embed0[b * H + j] = d * rsqrtf(var + LN_EPS) * lng[j] + lnb[j];
}

__global__ void bcast_kernel(const float* __restrict__ init0, const float* __restrict__ embed0,
                             float* __restrict__ h, float* __restrict__ c, float* __restrict__ embed,
                             long long total, int H, long long NH)
{
    long long idx = (long long)blockIdx.x * blockDim.x + threadIdx.x;
    if (idx >= total) return;
    int b = (int)(idx / NH);
    int j = (int)(idx & (H - 1));
    float hv = init0[b * H + j];
    h[idx] = hv;
    embed[idx] = embed0[b * H + j];
    c[idx] = 0.f;
}

// Fused LSTM cell elementwise + LayerNorm per node row.
__global__ __launch_bounds__(128)
void lstm_ln_kernel(const float* __restrict__ gates, float* __restrict__ c,
                    float* __restrict__ h, float* __restrict__ embed,
                    const float* __restrict__ lng, const float* __restrict__ lnb, int H)
{
    int r = blockIdx.x;
    int j = threadIdx.x;
    const float* grow = gates + (long long)r * 4 * H;
    float iv = grow[j], fv = grow[H + j], gv = grow[2 * H + j], ov = grow[3 * H + j];
    long long off = (long long)r * H + j;
    float cv = c[off];
    float ig = 1.f / (1.f + expf(-iv));
    float fg = 1.f / (1.f + expf(-fv));
    float og = 1.f / (1.f + expf(-ov));
    float cn = fg * cv + ig * tanhf(gv);
    float hn = og * tanhf(cn);
    c[off] = cn; h[off] = hn;

    __shared__ float red[128];
    red[j] = hn; __syncthreads();
    for (int s = 64; s > 0; s >>= 1) { if (j < s) red[j] += red[j + s]; __syncthreads(); }
    float mu = red[0] / (float)H;
    __syncthreads();
    float d = hn - mu;
    red[j] = d * d; __syncthreads();
    for (int s = 64; s > 0; s >>= 1) { if (j < s) red[j] += red[j + s]; __syncthreads(); }
    float var = red[0] / (float)H;
    embed[off] = d * rsqrtf(var + LN_EPS) * lng[j] + lnb[j];
}

// vote layer 3 (H->1) fused with mask-weighted sum and sigmoid.
__global__ __launch_bounds__(256)
void vote_kernel(const float* __restrict__ t2buf, const float* __restrict__ w3,
                 const float* __restrict__ b3p, const float* __restrict__ mask,
                 float* __restrict__ out, int N, int H)
{
    int b = blockIdx.x;
    int tid = threadIdx.x;
    __shared__ float sw[128];
    if (tid < H) sw[tid] = w3[tid];
    __syncthreads();
    float b3 = b3p[0];
    float acc = 0.f;
    for (int i = tid; i < N; i += blockDim.x) {
        const float* row = t2buf + ((long long)b * N + i) * H;
        float d = 0.f;
        for (int q = 0; q < H; ++q) d += row[q] * sw[q];
        acc += mask[(long long)b * N + i] * (d + b3);
    }
    __shared__ float red[256];
    red[tid] = acc; __syncthreads();
    for (int s = 128; s > 0; s >>= 1) { if (tid < s) red[tid] += red[tid + s]; __syncthreads(); }
    if (tid == 0) out[b] = 1.f / (1.f + expf(-red[0]));
}

extern "C" void kernel_launch(void* const* d_in, const int* in_sizes, int n_in,
                              void* d_out, int out_size, void* d_ws, size_t ws_size,
                              hipStream_t stream)
{
    const float* x    = (const float*)d_in[0];
    const float* kk   = (const float*)d_in[1];
    const float* nn   = (const float*)d_in[2];
    const float* mask = (const float*)d_in[3];
    const float* iw1  = (const float*)d_in[4];
    const float* ib1  = (const float*)d_in[5];
    const float* iw2  = (const float*)d_in[6];
    const float* ib2  = (const float*)d_in[7];
    const float* iw3  = (const float*)d_in[8];
    const float* ib3  = (const float*)d_in[9];
    const float* mw1  = (const float*)d_in[10];
    const float* mb1  = (const float*)d_in[11];
    const float* mw2  = (const float*)d_in[12];
    const float* mb2  = (const float*)d_in[13];
    const float* mw3  = (const float*)d_in[14];
    const float* mb3  = (const float*)d_in[15];
    const float* wih  = (const float*)d_in[16];
    const float* whh  = (const float*)d_in[17];
    const float* bih  = (const float*)d_in[18];
    const float* bhh  = (const float*)d_in[19];
    const float* lng  = (const float*)d_in[20];
    const float* lnb  = (const float*)d_in[21];
    const float* vw1  = (const float*)d_in[22];
    const float* vb1  = (const float*)d_in[23];
    const float* vw2  = (const float*)d_in[24];
    const float* vb2  = (const float*)d_in[25];
    const float* vw3  = (const float*)d_in[26];
    const float* vb3  = (const float*)d_in[27];
    float* out = (float*)d_out;

    const int B = in_sizes[1];        // 4
    const int H = in_sizes[5];        // 128
    const int N = in_sizes[3] / B;    // 4096
    const long long NH  = (long long)N * H;
    const long long BNH = (long long)B * NH;
    const int M = B * N;

    float* ws     = (float*)d_ws;
    float* h      = ws;
    float* c      = h + BNH;
    float* embed  = c + BNH;
    float* t1     = embed + BNH;
    float* t2     = t1 + BNH;
    float* m      = t2 + BNH;
    float* msg    = m + BNH;
    float* gates  = msg + BNH;            // 4*BNH
    float* init0  = gates + 4 * BNH;
    float* embed0 = init0 + (long long)B * H;

    init_kernel<<<B, H, 0, stream>>>(kk, nn, iw1, ib1, iw2, ib2, iw3, ib3, lng, lnb,
                                     init0, embed0, H);
    {
        long long nb = (BNH + 255) / 256;
        bcast_kernel<<<dim3((unsigned)nb), 256, 0, stream>>>(init0, embed0, h, c, embed, BNH, H, NH);
    }

    dim3 blkG(256);
    dim3 gridMlp(H / BN, M / BM, 1);          // 2 x 256
    dim3 gridAgg(H / BN, N / BM, B);          // 2 x 64 x 4
    dim3 gridGates(4 * H / BN, M / BM, 1);    // 8 x 256

    for (int it = 0; it < 8; ++it) {
        gemm_kernel<true, false, 1><<<gridMlp, blkG, 0, stream>>>(
            embed, mw1, mb1, nullptr, nullptr, nullptr, t1, M, H, H, 0, 0, 0);
        gemm_kernel<true, false, 1><<<gridMlp, blkG, 0, stream>>>(
            t1, mw2, mb2, nullptr, nullptr, nullptr, t2, M, H, H, 0, 0, 0);
        gemm_kernel<true, false, 0><<<gridMlp, blkG, 0, stream>>>(
            t2, mw3, mb3, nullptr, nullptr, nullptr, m, M, H, H, 0, 0, 0);
        // msg[b] = x[b] @ m[b]   (M=N nodes, K=N, Ncols=H), batched over z
        gemm_kernel<false, false, 0><<<gridAgg, blkG, 0, stream>>>(
            x, m, nullptr, nullptr, nullptr, nullptr, msg, N, H, N,
            (long long)N * N, NH, NH);
        // gates = msg@wih^T + bih + h@whh^T + bhh
        gemm_kernel<true, true, 0><<<gridGates, blkG, 0, stream>>>(
            msg, wih, bih, h, whh, bhh, gates, M, 4 * H, H, 0, 0, 0);
        lstm_ln_kernel<<<M, H, 0, stream>>>(gates, c, h, embed, lng, lnb, H);
    }

    gemm_kernel<true, false, 1><<<gridMlp, blkG, 0, stream>>>(
        embed, vw1, vb1, nullptr, nullptr, nullptr, t1, M, H, H, 0, 0, 0);
    gemm_kernel<true, false, 1><<<gridMlp, blkG, 0, stream>>>(
        t1, vw2, vb2, nullptr, nullptr, nullptr, t2, M, H, H, 0, 0, 0);
    vote_kernel<<<B, 256, 0, stream>>>(t2, vw3, vb3, mask, out, N, H);
}

// Round 2
// 2528.184 us; speedup vs baseline: 1.6057x; 1.6057x over previous
//
#include <hip/hip_runtime.h>
#include <cstddef>

#define LN_EPS 1e-5f

typedef __attribute__((ext_vector_type(8))) short bf16x8;
typedef __attribute__((ext_vector_type(4))) float f32x4;

__device__ inline unsigned short f2bf(float f) {
    unsigned u = __float_as_uint(f);
    u += 0x7FFFu + ((u >> 16) & 1u);   // round-to-nearest-even
    return (unsigned short)(u >> 16);
}

constexpr int BM = 64, BN = 64, BK = 16;

template<bool TRANSB, bool DUAL, int ACT, int OUTT>
__global__ __launch_bounds__(256)
void gemm_kernel(const float* __restrict__ A, const float* __restrict__ Bm,
                 const float* __restrict__ bias,
                 const float* __restrict__ A2, const float* __restrict__ B2,
                 const float* __restrict__ bias2,
                 float* __restrict__ C,
                 int M, int Ncols, int K,
                 long long sAb, long long sBb, long long sCb, int nPerBatch)
{
    __shared__ float sA[BK][BM + 4];
    __shared__ float sB[BK][BN + 4];

    const int bn = blockIdx.x * BN;
    const int bm = blockIdx.y * BM;
    const long long z = blockIdx.z;

    const int t  = threadIdx.x;
    const int tx = t & 15, ty = t >> 4;

    float acc[4][4];
#pragma unroll
    for (int i = 0; i < 4; ++i)
#pragma unroll
        for (int j = 0; j < 4; ++j) acc[i][j] = 0.f;

#pragma unroll
    for (int phase = 0; phase < (DUAL ? 2 : 1); ++phase) {
        const float* Ap = (phase == 0 ? A : A2) + z * sAb;
        const float* Bp = (phase == 0 ? Bm : B2) + z * sBb;

        for (int k0 = 0; k0 < K; k0 += BK) {
            {
                int mm = t >> 2;
                int kq = (t & 3) << 2;
                const float4 av = *(const float4*)(Ap + (long long)(bm + mm) * K + k0 + kq);
                sA[kq + 0][mm] = av.x; sA[kq + 1][mm] = av.y;
                sA[kq + 2][mm] = av.z; sA[kq + 3][mm] = av.w;
            }
            if (TRANSB) {
                int nn = t >> 2;
                int kq = (t & 3) << 2;
                const float4 bv = *(const float4*)(Bp + (long long)(bn + nn) * K + k0 + kq);
                sB[kq + 0][nn] = bv.x; sB[kq + 1][nn] = bv.y;
                sB[kq + 2][nn] = bv.z; sB[kq + 3][nn] = bv.w;
            } else {
                int kk = t >> 4;
                int nq = (t & 15) << 2;
                const float4 bv = *(const float4*)(Bp + (long long)(k0 + kk) * Ncols + bn + nq);
                *(float4*)&sB[kk][nq] = bv;
            }
            __syncthreads();
#pragma unroll
            for (int k = 0; k < BK; ++k) {
                float a0 = sA[k][ty * 4 + 0], a1 = sA[k][ty * 4 + 1];
                float a2 = sA[k][ty * 4 + 2], a3 = sA[k][ty * 4 + 3];
                float b0 = sB[k][tx * 4 + 0], b1 = sB[k][tx * 4 + 1];
                float b2 = sB[k][tx * 4 + 2], b3 = sB[k][tx * 4 + 3];
                acc[0][0] += a0 * b0; acc[0][1] += a0 * b1; acc[0][2] += a0 * b2; acc[0][3] += a0 * b3;
                acc[1][0] += a1 * b0; acc[1][1] += a1 * b1; acc[1][2] += a1 * b2; acc[1][3] += a1 * b3;
                acc[2][0] += a2 * b0; acc[2][1] += a2 * b1; acc[2][2] += a2 * b2; acc[2][3] += a2 * b3;
                acc[3][0] += a3 * b0; acc[3][1] += a3 * b1; acc[3][2] += a3 * b2; acc[3][3] += a3 * b3;
            }
            __syncthreads();
        }
    }

    if (OUTT == 0) {
        float* Cp = C + z * sCb;
#pragma unroll
        for (int i = 0; i < 4; ++i) {
            int row = bm + ty * 4 + i;
#pragma unroll
            for (int j = 0; j < 4; ++j) {
                int col = bn + tx * 4 + j;
                float v = acc[i][j];
                if (bias) v += bias[col];
                if (DUAL && bias2) v += bias2[col];
                if (ACT == 1) v = v > 0.f ? v : 0.f;
                Cp[(long long)row * Ncols + col] = v;
            }
        }
    } else {
        unsigned short* Cb = (unsigned short*)C;
        int batch = bm / nPerBatch;
        int r0 = bm - batch * nPerBatch + ty * 4;
#pragma unroll
        for (int j = 0; j < 4; ++j) {
            int col = bn + tx * 4 + j;
            float vv[4];
#pragma unroll
            for (int i = 0; i < 4; ++i) {
                float v1 = acc[i][j];
                if (bias) v1 += bias[col];
                if (ACT == 1) v1 = v1 > 0.f ? v1 : 0.f;
                vv[i] = v1;
            }
            ushort4 v;
            v.x = f2bf(vv[0]); v.y = f2bf(vv[1]); v.z = f2bf(vv[2]); v.w = f2bf(vv[3]);
            *(ushort4*)&Cb[((long long)batch * Ncols + col) * nPerBatch + r0] = v;
        }
    }
}

// MFMA aggregation: msg[b] = x[b] @ m[b]; barrier-free, LDS-free, reg-pipelined.
template<bool XB>
__global__ __launch_bounds__(256, 2)
void agg_kernel(const float* __restrict__ xf, const unsigned short* __restrict__ xb,
                const unsigned short* __restrict__ mt, float* __restrict__ msg,
                int N, int H)
{
    const int lane = threadIdx.x & 63;
    const int wave = threadIdx.x >> 6;
    const int lr = lane & 15, lq = lane >> 4;
    const int batch = blockIdx.y;
    const int rowBase = (blockIdx.x * 4 + wave) * 16;
    const int arow = rowBase + lr;

    const long long xoff = (long long)batch * N * N + (long long)arow * N + lq * 8;
    const unsigned short* mtb = mt + (long long)batch * H * N;

    f32x4 acc[8];
#pragma unroll
    for (int i = 0; i < 8; ++i) acc[i] = (f32x4)(0.f);

    const unsigned short* ab = xb + xoff;
    const float*          af = xf + xoff;

    const unsigned short* bp[8];
#pragma unroll
    for (int tn = 0; tn < 8; ++tn)
        bp[tn] = mtb + (long long)(tn * 16 + lr) * N + lq * 8;

    auto loadA = [&](int k0) -> bf16x8 {
        if (XB) {
            return *(const bf16x8*)(ab + k0);
        } else {
            float4 lo = *(const float4*)(af + k0);
            float4 hi = *(const float4*)(af + k0 + 4);
            bf16x8 r;
            r[0] = (short)f2bf(lo.x); r[1] = (short)f2bf(lo.y);
            r[2] = (short)f2bf(lo.z); r[3] = (short)f2bf(lo.w);
            r[4] = (short)f2bf(hi.x); r[5] = (short)f2bf(hi.y);
            r[6] = (short)f2bf(hi.z); r[7] = (short)f2bf(hi.w);
            return r;
        }
    };

    bf16x8 a0 = loadA(0);
    bf16x8 b0[8];
#pragma unroll
    for (int tn = 0; tn < 8; ++tn) b0[tn] = *(const bf16x8*)(bp[tn]);

    for (int k0 = 32; k0 < N; k0 += 32) {
        bf16x8 a1 = loadA(k0);
        bf16x8 b1[8];
#pragma unroll
        for (int tn = 0; tn < 8; ++tn) b1[tn] = *(const bf16x8*)(bp[tn] + k0);
#pragma unroll
        for (int tn = 0; tn < 8; ++tn)
            acc[tn] = __builtin_amdgcn_mfma_f32_16x16x32_bf16(a0, b0[tn], acc[tn], 0, 0, 0);
        a0 = a1;
#pragma unroll
        for (int tn = 0; tn < 8; ++tn) b0[tn] = b1[tn];
    }
#pragma unroll
    for (int tn = 0; tn < 8; ++tn)
        acc[tn] = __builtin_amdgcn_mfma_f32_16x16x32_bf16(a0, b0[tn], acc[tn], 0, 0, 0);

    float* mrow = msg + (long long)batch * N * H;
#pragma unroll
    for (int tn = 0; tn < 8; ++tn)
#pragma unroll
        for (int r = 0; r < 4; ++r)
            mrow[(long long)(rowBase + lq * 4 + r) * H + tn * 16 + lr] = acc[tn][r];
}

__global__ void cast_kernel(const float* __restrict__ x, unsigned short* __restrict__ xb,
                            long long n4)
{
    long long i = ((long long)blockIdx.x * blockDim.x + threadIdx.x);
    if (i >= n4) return;
    float4 v = *(const float4*)(x + i * 4);
    ushort4 o;
    o.x = f2bf(v.x); o.y = f2bf(v.y); o.z = f2bf(v.z); o.w = f2bf(v.w);
    *(ushort4*)&xb[i * 4] = o;
}

__global__ __launch_bounds__(128)
void init_kernel(const float* __restrict__ kk, const float* __restrict__ nn,
                 const float* __restrict__ w1, const float* __restrict__ b1,
                 const float* __restrict__ w2, const float* __restrict__ b2,
                 const float* __restrict__ w3, const float* __restrict__ b3,
                 const float* __restrict__ lng, const float* __restrict__ lnb,
                 float* __restrict__ init0, float* __restrict__ embed0, int H)
{
    int b = blockIdx.x, j = threadIdx.x;
    __shared__ float s1[128];
    __shared__ float s2[128];
    __shared__ float red[128];
    float kv = kk[b], nv = nn[b];
    float h1 = w1[j * 2 + 0] * kv + w1[j * 2 + 1] * nv + b1[j];
    h1 = h1 > 0.f ? h1 : 0.f;
    s1[j] = h1; __syncthreads();
    float h2 = b2[j];
    for (int q = 0; q < H; ++q) h2 += w2[j * H + q] * s1[q];
    h2 = h2 > 0.f ? h2 : 0.f;
    s2[j] = h2; __syncthreads();
    float o = b3[j];
    for (int q = 0; q < H; ++q) o += w3[j * H + q] * s2[q];
    init0[b * H + j] = o;

    red[j] = o; __syncthreads();
    for (int s = 64; s > 0; s >>= 1) { if (j < s) red[j] += red[j + s]; __syncthreads(); }
    float mu = red[0] / (float)H;
    __syncthreads();
    float d = o - mu;
    red[j] = d * d; __syncthreads();
    for (int s = 64; s > 0; s >>= 1) { if (j < s) red[j] += red[j + s]; __syncthreads(); }
    float var = red[0] / (float)H;
    embed0[b * H + j] = d * rsqrtf(var + LN_EPS) * lng[j] + lnb[j];
}

__global__ void bcast_kernel(const float* __restrict__ init0, const float* __restrict__ embed0,
                             float* __restrict__ h, float* __restrict__ c, float* __restrict__ embed,
                             long long total, int H, long long NH)
{
    long long idx = (long long)blockIdx.x * blockDim.x + threadIdx.x;
    if (idx >= total) return;
    int b = (int)(idx / NH);
    int j = (int)(idx & (H - 1));
    float hv = init0[b * H + j];
    h[idx] = hv;
    embed[idx] = embed0[b * H + j];
    c[idx] = 0.f;
}

__global__ __launch_bounds__(128)
void lstm_ln_kernel(const float* __restrict__ gates, float* __restrict__ c,
                    float* __restrict__ h, float* __restrict__ embed,
                    const float* __restrict__ lng, const float* __restrict__ lnb, int H)
{
    int r = blockIdx.x;
    int j = threadIdx.x;
    const float* grow = gates + (long long)r * 4 * H;
    float iv = grow[j], fv = grow[H + j], gv = grow[2 * H + j], ov = grow[3 * H + j];
    long long off = (long long)r * H + j;
    float cv = c[off];
    float ig = 1.f / (1.f + expf(-iv));
    float fg = 1.f / (1.f + expf(-fv));
    float og = 1.f / (1.f + expf(-ov));
    float cn = fg * cv + ig * tanhf(gv);
    float hn = og * tanhf(cn);
    c[off] = cn; h[off] = hn;

    __shared__ float red[128];
    red[j] = hn; __syncthreads();
    for (int s = 64; s > 0; s >>= 1) { if (j < s) red[j] += red[j + s]; __syncthreads(); }
    float mu = red[0] / (float)H;
    __syncthreads();
    float d = hn - mu;
    red[j] = d * d; __syncthreads();
    for (int s = 64; s > 0; s >>= 1) { if (j < s) red[j] += red[j + s]; __syncthreads(); }
    float var = red[0] / (float)H;
    embed[off] = d * rsqrtf(var + LN_EPS) * lng[j] + lnb[j];
}

__global__ __launch_bounds__(256)
void vote_kernel(const float* __restrict__ t2buf, const float* __restrict__ w3,
                 const float* __restrict__ b3p, const float* __restrict__ mask,
                 float* __restrict__ out, int N, int H)
{
    int b = blockIdx.x;
    int tid = threadIdx.x;
    __shared__ float sw[128];
    if (tid < H) sw[tid] = w3[tid];
    __syncthreads();
    float b3 = b3p[0];
    float acc = 0.f;
    for (int i = tid; i < N; i += blockDim.x) {
        const float* row = t2buf + ((long long)b * N + i) * H;
        float d = 0.f;
        for (int q = 0; q < H; ++q) d += row[q] * sw[q];
        acc += mask[(long long)b * N + i] * (d + b3);
    }
    __shared__ float red[256];
    red[tid] = acc; __syncthreads();
    for (int s = 128; s > 0; s >>= 1) { if (tid < s) red[tid] += red[tid + s]; __syncthreads(); }
    if (tid == 0) out[b] = 1.f / (1.f + expf(-red[0]));
}

extern "C" void kernel_launch(void* const* d_in, const int* in_sizes, int n_in,
                              void* d_out, int out_size, void* d_ws, size_t ws_size,
                              hipStream_t stream)
{
    const float* x    = (const float*)d_in[0];
    const float* kk   = (const float*)d_in[1];
    const float* nn   = (const float*)d_in[2];
    const float* mask = (const float*)d_in[3];
    const float* iw1  = (const float*)d_in[4];
    const float* ib1  = (const float*)d_in[5];
    const float* iw2  = (const float*)d_in[6];
    const float* ib2  = (const float*)d_in[7];
    const float* iw3  = (const float*)d_in[8];
    const float* ib3  = (const float*)d_in[9];
    const float* mw1  = (const float*)d_in[10];
    const float* mb1  = (const float*)d_in[11];
    const float* mw2  = (const float*)d_in[12];
    const float* mb2  = (const float*)d_in[13];
    const float* mw3  = (const float*)d_in[14];
    const float* mb3  = (const float*)d_in[15];
    const float* wih  = (const float*)d_in[16];
    const float* whh  = (const float*)d_in[17];
    const float* bih  = (const float*)d_in[18];
    const float* bhh  = (const float*)d_in[19];
    const float* lng  = (const float*)d_in[20];
    const float* lnb  = (const float*)d_in[21];
    const float* vw1  = (const float*)d_in[22];
    const float* vb1  = (const float*)d_in[23];
    const float* vw2  = (const float*)d_in[24];
    const float* vb2  = (const float*)d_in[25];
    const float* vw3  = (const float*)d_in[26];
    const float* vb3  = (const float*)d_in[27];
    float* out = (float*)d_out;

    const int B = in_sizes[1];        // 4
    const int H = in_sizes[5];        // 128
    const int N = in_sizes[3] / B;    // 4096
    const long long NH  = (long long)N * H;
    const long long BNH = (long long)B * NH;
    const int M = B * N;

    float* ws     = (float*)d_ws;
    float* h      = ws;
    float* c      = h + BNH;
    float* embed  = c + BNH;
    float* t1     = embed + BNH;
    float* t2     = t1 + BNH;
    float* msg    = t2 + BNH;
    float* gates  = msg + BNH;                                  // 4*BNH floats
    unsigned short* m_t = (unsigned short*)(gates + 4 * BNH);   // BNH bf16
    float* init0  = (float*)(m_t + BNH);
    float* embed0 = init0 + (long long)B * H;
    unsigned short* x_bf = (unsigned short*)(embed0 + (long long)B * H);

    const long long base_bytes = (long long)((char*)x_bf - (char*)d_ws);
    const long long xb_bytes   = 2LL * B * N * N;
    const bool use_xb = ((long long)ws_size >= base_bytes + xb_bytes + 256);

    init_kernel<<<B, H, 0, stream>>>(kk, nn, iw1, ib1, iw2, ib2, iw3, ib3, lng, lnb,
                                     init0, embed0, H);
    {
        long long nb = (BNH + 255) / 256;
        bcast_kernel<<<dim3((unsigned)nb), 256, 0, stream>>>(init0, embed0, h, c, embed, BNH, H, NH);
    }
    if (use_xb) {
        long long n4 = (long long)B * N * N / 4;
        cast_kernel<<<dim3((unsigned)((n4 + 255) / 256)), 256, 0, stream>>>(x, x_bf, n4);
    }

    dim3 blkG(256);
    dim3 gridMlp(H / BN, M / BM, 1);
    dim3 gridAgg(N / 64, B, 1);
    dim3 gridGates(4 * H / BN, M / BM, 1);

    for (int it = 0; it < 8; ++it) {
        gemm_kernel<true, false, 1, 0><<<gridMlp, blkG, 0, stream>>>(
            embed, mw1, mb1, nullptr, nullptr, nullptr, t1, M, H, H, 0, 0, 0, N);
        gemm_kernel<true, false, 1, 0><<<gridMlp, blkG, 0, stream>>>(
            t1, mw2, mb2, nullptr, nullptr, nullptr, t2, M, H, H, 0, 0, 0, N);
        gemm_kernel<true, false, 0, 1><<<gridMlp, blkG, 0, stream>>>(
            t2, mw3, mb3, nullptr, nullptr, nullptr, (float*)m_t, M, H, H, 0, 0, 0, N);
        if (use_xb)
            agg_kernel<true><<<gridAgg, blkG, 0, stream>>>(nullptr, x_bf, m_t, msg, N, H);
        else
            agg_kernel<false><<<gridAgg, blkG, 0, stream>>>(x, nullptr, m_t, msg, N, H);
        gemm_kernel<true, true, 0, 0><<<gridGates, blkG, 0, stream>>>(
            msg, wih, bih, h, whh, bhh, gates, M, 4 * H, H, 0, 0, 0, N);
        lstm_ln_kernel<<<M, H, 0, stream>>>(gates, c, h, embed, lng, lnb, H);
    }

    gemm_kernel<true, false, 1, 0><<<gridMlp, blkG, 0, stream>>>(
        embed, vw1, vb1, nullptr, nullptr, nullptr, t1, M, H, H, 0, 0, 0, N);
    gemm_kernel<true, false, 1, 0><<<gridMlp, blkG, 0, stream>>>(
        t1, vw2, vb2, nullptr, nullptr, nullptr, t2, M, H, H, 0, 0, 0, N);
    vote_kernel<<<B, 256, 0, stream>>>(t2, vw3, vb3, mask, out, N, H);
}

// Round 3
// 2030.578 us; speedup vs baseline: 1.9992x; 1.2451x over previous
//
#include <hip/hip_runtime.h>
#include <cstddef>

#define LN_EPS 1e-5f

typedef __attribute__((ext_vector_type(8))) short bf16x8;
typedef __attribute__((ext_vector_type(4))) float f32x4;

__device__ __forceinline__ unsigned short f2bf(float f) {
    unsigned u = __float_as_uint(f);
    u += 0x7FFFu + ((u >> 16) & 1u);   // round-to-nearest-even
    return (unsigned short)(u >> 16);
}
__device__ __forceinline__ float sigf(float x) { return 1.f / (1.f + __expf(-x)); }

// One K=128 -> 128-col MFMA layer. W is bf16 [128 out][128 in] (torch layout).
__device__ __forceinline__ void layer128(const unsigned short* __restrict__ W,
                                         const bf16x8 a[4], f32x4 acc[8],
                                         int lr, int lq)
{
#pragma unroll
    for (int s = 0; s < 4; ++s) {
#pragma unroll
        for (int tn = 0; tn < 8; ++tn) {
            bf16x8 b = *(const bf16x8*)(W + (tn * 16 + lr) * 128 + s * 32 + lq * 8);
            acc[tn] = __builtin_amdgcn_mfma_f32_16x16x32_bf16(a[s], b, acc[tn], 0, 0, 0);
        }
    }
}

// ---------------- fused msg MLP: embed(bf16) -> 3 layers -> m_t (bf16, [B][H][N]) ----
__global__ __launch_bounds__(256)
void msg_mlp_kernel(const unsigned short* __restrict__ embed,
                    const unsigned short* __restrict__ w1, const float* __restrict__ b1,
                    const unsigned short* __restrict__ w2, const float* __restrict__ b2,
                    const unsigned short* __restrict__ w3, const float* __restrict__ b3,
                    unsigned short* __restrict__ m_t, int N)
{
    __shared__ unsigned short sact[4][16][136];   // per-wave staging (row stride 272B, 16B-aligned)
    const int lane = threadIdx.x & 63, wave = threadIdx.x >> 6;
    const int lr = lane & 15, lq = lane >> 4;
    const int r0 = (blockIdx.x * 4 + wave) * 16;

    bf16x8 a[4];
    f32x4 acc[8];

#pragma unroll
    for (int s = 0; s < 4; ++s)
        a[s] = *(const bf16x8*)(embed + (long long)(r0 + lr) * 128 + s * 32 + lq * 8);
#pragma unroll
    for (int tn = 0; tn < 8; ++tn) acc[tn] = (f32x4)(0.f);
    layer128(w1, a, acc, lr, lq);

#pragma unroll
    for (int tn = 0; tn < 8; ++tn) {
        float bb = b1[tn * 16 + lr];
#pragma unroll
        for (int r = 0; r < 4; ++r) {
            float v = acc[tn][r] + bb; v = v > 0.f ? v : 0.f;
            sact[wave][lq * 4 + r][tn * 16 + lr] = f2bf(v);
        }
    }
    __syncthreads();
#pragma unroll
    for (int s = 0; s < 4; ++s)
        a[s] = *(const bf16x8*)&sact[wave][lr][s * 32 + lq * 8];
#pragma unroll
    for (int tn = 0; tn < 8; ++tn) acc[tn] = (f32x4)(0.f);
    layer128(w2, a, acc, lr, lq);

#pragma unroll
    for (int tn = 0; tn < 8; ++tn) {
        float bb = b2[tn * 16 + lr];
#pragma unroll
        for (int r = 0; r < 4; ++r) {
            float v = acc[tn][r] + bb; v = v > 0.f ? v : 0.f;
            sact[wave][lq * 4 + r][tn * 16 + lr] = f2bf(v);
        }
    }
    __syncthreads();
#pragma unroll
    for (int s = 0; s < 4; ++s)
        a[s] = *(const bf16x8*)&sact[wave][lr][s * 32 + lq * 8];
#pragma unroll
    for (int tn = 0; tn < 8; ++tn) acc[tn] = (f32x4)(0.f);
    layer128(w3, a, acc, lr, lq);

    const int batch = r0 / N;                 // blocks never straddle batches (N % 64 == 0)
    const int rin0 = r0 - batch * N + lq * 4;
#pragma unroll
    for (int tn = 0; tn < 8; ++tn) {
        float bb = b3[tn * 16 + lr];
        ushort4 o;
        o.x = f2bf(acc[tn][0] + bb); o.y = f2bf(acc[tn][1] + bb);
        o.z = f2bf(acc[tn][2] + bb); o.w = f2bf(acc[tn][3] + bb);
        *(ushort4*)(m_t + ((long long)(batch * 128 + tn * 16 + lr)) * N + rin0) = o;
    }
}

// ---------------- aggregation: msg[b] = x[b] @ m[b]; K-split over 4 waves --------------
template<bool XB>
__global__ __launch_bounds__(256)
void agg_kernel(const float* __restrict__ xf, const unsigned short* __restrict__ xb,
                const unsigned short* __restrict__ mt, unsigned short* __restrict__ msgout,
                int N)
{
    __shared__ float sacc[4][16][132];
    const int lane = threadIdx.x & 63, wave = threadIdx.x >> 6;
    const int lr = lane & 15, lq = lane >> 4;
    const int batch = blockIdx.y;
    const int rowBase = blockIdx.x * 16;
    const int kBase = wave * (N >> 2);
    const int kIters = N >> 7;                 // (N/4)/32

    const long long xoff = (long long)batch * N * N + (long long)(rowBase + lr) * N + kBase + lq * 8;
    const unsigned short* ab = xb + xoff;
    const float*          af = xf + xoff;
    const long long bbase = (long long)batch * 128 * N + (long long)lr * N + kBase + lq * 8;

    f32x4 acc[8];
#pragma unroll
    for (int tn = 0; tn < 8; ++tn) acc[tn] = (f32x4)(0.f);

    auto loadA = [&](int k) -> bf16x8 {
        if (XB) {
            return *(const bf16x8*)(ab + k);
        } else {
            float4 lo = *(const float4*)(af + k);
            float4 hi = *(const float4*)(af + k + 4);
            bf16x8 r;
            r[0] = (short)f2bf(lo.x); r[1] = (short)f2bf(lo.y);
            r[2] = (short)f2bf(lo.z); r[3] = (short)f2bf(lo.w);
            r[4] = (short)f2bf(hi.x); r[5] = (short)f2bf(hi.y);
            r[6] = (short)f2bf(hi.z); r[7] = (short)f2bf(hi.w);
            return r;
        }
    };

    bf16x8 a0 = loadA(0);
    bf16x8 b0[8], b1[8];
#pragma unroll
    for (int tn = 0; tn < 8; ++tn)
        b0[tn] = *(const bf16x8*)(mt + bbase + (long long)tn * 16 * N);

    for (int it = 1; it < kIters; ++it) {
        const int k = it * 32;
        bf16x8 a1 = loadA(k);
#pragma unroll
        for (int tn = 0; tn < 8; ++tn)
            b1[tn] = *(const bf16x8*)(mt + bbase + (long long)tn * 16 * N + k);
#pragma unroll
        for (int tn = 0; tn < 8; ++tn)
            acc[tn] = __builtin_amdgcn_mfma_f32_16x16x32_bf16(a0, b0[tn], acc[tn], 0, 0, 0);
        a0 = a1;
#pragma unroll
        for (int tn = 0; tn < 8; ++tn) b0[tn] = b1[tn];
    }
#pragma unroll
    for (int tn = 0; tn < 8; ++tn)
        acc[tn] = __builtin_amdgcn_mfma_f32_16x16x32_bf16(a0, b0[tn], acc[tn], 0, 0, 0);

#pragma unroll
    for (int tn = 0; tn < 8; ++tn)
#pragma unroll
        for (int r = 0; r < 4; ++r)
            sacc[wave][lq * 4 + r][tn * 16 + lr] = acc[tn][r];
    __syncthreads();
    {
        const int t = threadIdx.x;
        const int row = t >> 4, cb2 = (t & 15) * 8;
        unsigned short o[8];
#pragma unroll
        for (int j = 0; j < 8; ++j) {
            float v = sacc[0][row][cb2 + j] + sacc[1][row][cb2 + j]
                    + sacc[2][row][cb2 + j] + sacc[3][row][cb2 + j];
            o[j] = f2bf(v);
        }
        unsigned short* dst = msgout + (long long)(batch * N + rowBase + row) * 128 + cb2;
        *(ushort4*)dst = *(ushort4*)&o[0];
        *(ushort4*)(dst + 4) = *(ushort4*)&o[4];
    }
}

// ---------------- fused dual-GEMM gates + LSTM cell + LayerNorm ------------------------
__global__ __launch_bounds__(256)
void gates_lstm_kernel(const unsigned short* __restrict__ msg,
                       unsigned short* hb, float* cb,
                       const unsigned short* __restrict__ wih,
                       const unsigned short* __restrict__ whh,
                       const float* __restrict__ bih, const float* __restrict__ bhh,
                       const float* __restrict__ lng, const float* __restrict__ lnb,
                       unsigned short* __restrict__ embed_out)
{
    const int lane = threadIdx.x & 63, wave = threadIdx.x >> 6;
    const int lr = lane & 15, lq = lane >> 4;
    const int tileIdx = blockIdx.x * 4 + wave;
    const int r0 = tileIdx * 16;

    f32x4 acc[32];
#pragma unroll
    for (int t = 0; t < 32; ++t) acc[t] = (f32x4)(0.f);

    bf16x8 a[4];
#pragma unroll
    for (int s = 0; s < 4; ++s)
        a[s] = *(const bf16x8*)(msg + (long long)(r0 + lr) * 128 + s * 32 + lq * 8);
#pragma unroll
    for (int s = 0; s < 4; ++s)
#pragma unroll
        for (int tn = 0; tn < 32; ++tn) {
            bf16x8 b = *(const bf16x8*)(wih + (tn * 16 + lr) * 128 + s * 32 + lq * 8);
            acc[tn] = __builtin_amdgcn_mfma_f32_16x16x32_bf16(a[s], b, acc[tn], 0, 0, 0);
        }
#pragma unroll
    for (int s = 0; s < 4; ++s)
        a[s] = *(const bf16x8*)((const unsigned short*)hb + (long long)(r0 + lr) * 128 + s * 32 + lq * 8);
#pragma unroll
    for (int s = 0; s < 4; ++s)
#pragma unroll
        for (int tn = 0; tn < 32; ++tn) {
            bf16x8 b = *(const bf16x8*)(whh + (tn * 16 + lr) * 128 + s * 32 + lq * 8);
            acc[tn] = __builtin_amdgcn_mfma_f32_16x16x32_bf16(a[s], b, acc[tn], 0, 0, 0);
        }

    // LSTM elementwise. col = tn*16+lr; i/f/g/o of a column all live in this lane.
    float hn[8][4];
    float4* cw = (float4*)cb;   // tiled: [(tileIdx*8+tn)*64 + lane] -> float4 (r=0..3)
#pragma unroll
    for (int tn = 0; tn < 8; ++tn) {
        const int col = tn * 16 + lr;
        const float bi  = bih[col]       + bhh[col];
        const float bf_ = bih[col + 128] + bhh[col + 128];
        const float bg  = bih[col + 256] + bhh[col + 256];
        const float bo  = bih[col + 384] + bhh[col + 384];
        float4 cold = cw[(tileIdx * 8 + tn) * 64 + lane];
        float co[4] = {cold.x, cold.y, cold.z, cold.w};
        float cn[4];
#pragma unroll
        for (int r = 0; r < 4; ++r) {
            float iv = acc[tn][r]      + bi;
            float fv = acc[tn + 8][r]  + bf_;
            float gv = acc[tn + 16][r] + bg;
            float ov = acc[tn + 24][r] + bo;
            float cc = sigf(fv) * co[r] + sigf(iv) * tanhf(gv);
            cn[r] = cc;
            hn[tn][r] = sigf(ov) * tanhf(cc);
        }
        float4 cnew = {cn[0], cn[1], cn[2], cn[3]};
        cw[(tileIdx * 8 + tn) * 64 + lane] = cnew;
    }

    // LayerNorm per row (row = lq*4+r); cols spread over the 16 lanes sharing lq.
    float mu[4], rs[4];
#pragma unroll
    for (int r = 0; r < 4; ++r) {
        float s1 = 0.f, s2 = 0.f;
#pragma unroll
        for (int tn = 0; tn < 8; ++tn) { float v = hn[tn][r]; s1 += v; s2 += v * v; }
#pragma unroll
        for (int m = 1; m <= 8; m <<= 1) {
            s1 += __shfl_xor(s1, m);
            s2 += __shfl_xor(s2, m);
        }
        float mean = s1 * (1.f / 128.f);
        float var  = s2 * (1.f / 128.f) - mean * mean;
        mu[r] = mean;
        rs[r] = rsqrtf(var + LN_EPS);
    }

#pragma unroll
    for (int tn = 0; tn < 8; ++tn) {
        const int col = tn * 16 + lr;
        const float g = lng[col], bb = lnb[col];
#pragma unroll
        for (int r = 0; r < 4; ++r) {
            long long off = (long long)(r0 + lq * 4 + r) * 128 + col;
            hb[off] = f2bf(hn[tn][r]);
            embed_out[off] = f2bf((hn[tn][r] - mu[r]) * rs[r] * g + bb);
        }
    }
}

// ---------------- fused vote MLP (2 layers) + layer3 dot + masked sum ------------------
__global__ __launch_bounds__(256)
void vote_mlp_kernel(const unsigned short* __restrict__ embed,
                     const unsigned short* __restrict__ w1, const float* __restrict__ b1,
                     const unsigned short* __restrict__ w2, const float* __restrict__ b2,
                     const float* __restrict__ w3, const float* __restrict__ b3p,
                     const float* __restrict__ mask, float* __restrict__ logit, int N)
{
    __shared__ unsigned short sact[4][16][136];
    const int lane = threadIdx.x & 63, wave = threadIdx.x >> 6;
    const int lr = lane & 15, lq = lane >> 4;
    const int r0 = (blockIdx.x * 4 + wave) * 16;

    bf16x8 a[4];
    f32x4 acc[8];
#pragma unroll
    for (int s = 0; s < 4; ++s)
        a[s] = *(const bf16x8*)(embed + (long long)(r0 + lr) * 128 + s * 32 + lq * 8);
#pragma unroll
    for (int tn = 0; tn < 8; ++tn) acc[tn] = (f32x4)(0.f);
    layer128(w1, a, acc, lr, lq);

#pragma unroll
    for (int tn = 0; tn < 8; ++tn) {
        float bb = b1[tn * 16 + lr];
#pragma unroll
        for (int r = 0; r < 4; ++r) {
            float v = acc[tn][r] + bb; v = v > 0.f ? v : 0.f;
            sact[wave][lq * 4 + r][tn * 16 + lr] = f2bf(v);
        }
    }
    __syncthreads();
#pragma unroll
    for (int s = 0; s < 4; ++s)
        a[s] = *(const bf16x8*)&sact[wave][lr][s * 32 + lq * 8];
#pragma unroll
    for (int tn = 0; tn < 8; ++tn) acc[tn] = (f32x4)(0.f);
    layer128(w2, a, acc, lr, lq);

    float dot[4] = {0.f, 0.f, 0.f, 0.f};
#pragma unroll
    for (int tn = 0; tn < 8; ++tn) {
        const int col = tn * 16 + lr;
        const float bb = b2[col], w3c = w3[col];
#pragma unroll
        for (int r = 0; r < 4; ++r) {
            float v = acc[tn][r] + bb; v = v > 0.f ? v : 0.f;
            dot[r] += v * w3c;
        }
    }
#pragma unroll
    for (int r = 0; r < 4; ++r)
#pragma unroll
        for (int m = 1; m <= 8; m <<= 1) dot[r] += __shfl_xor(dot[r], m);

    const int batch = r0 / N;
    const float b3 = b3p[0];
    const int base = r0 + lq * 4;
    float wsum = mask[base + 0] * (dot[0] + b3) + mask[base + 1] * (dot[1] + b3)
               + mask[base + 2] * (dot[2] + b3) + mask[base + 3] * (dot[3] + b3);
    float t = (lr == 0) ? wsum : 0.f;
    t += __shfl_xor(t, 16);
    t += __shfl_xor(t, 32);
    if (lane == 0) atomicAdd(&logit[batch], t);
}

// ---------------- small kernels --------------------------------------------------------
__global__ __launch_bounds__(128)
void init_kernel(const float* __restrict__ kk, const float* __restrict__ nn,
                 const float* __restrict__ w1, const float* __restrict__ b1,
                 const float* __restrict__ w2, const float* __restrict__ b2,
                 const float* __restrict__ w3, const float* __restrict__ b3,
                 const float* __restrict__ lng, const float* __restrict__ lnb,
                 float* __restrict__ init0, float* __restrict__ embed0,
                 float* __restrict__ logit, int H)
{
    int b = blockIdx.x, j = threadIdx.x;
    __shared__ float s1[128];
    __shared__ float s2[128];
    __shared__ float red[128];
    if (j == 0) logit[b] = 0.f;
    float kv = kk[b], nv = nn[b];
    float h1 = w1[j * 2 + 0] * kv + w1[j * 2 + 1] * nv + b1[j];
    h1 = h1 > 0.f ? h1 : 0.f;
    s1[j] = h1; __syncthreads();
    float h2 = b2[j];
    for (int q = 0; q < H; ++q) h2 += w2[j * H + q] * s1[q];
    h2 = h2 > 0.f ? h2 : 0.f;
    s2[j] = h2; __syncthreads();
    float o = b3[j];
    for (int q = 0; q < H; ++q) o += w3[j * H + q] * s2[q];
    init0[b * H + j] = o;

    red[j] = o; __syncthreads();
    for (int s = 64; s > 0; s >>= 1) { if (j < s) red[j] += red[j + s]; __syncthreads(); }
    float mu = red[0] / (float)H;
    __syncthreads();
    float d = o - mu;
    red[j] = d * d; __syncthreads();
    for (int s = 64; s > 0; s >>= 1) { if (j < s) red[j] += red[j + s]; __syncthreads(); }
    float var = red[0] / (float)H;
    embed0[b * H + j] = d * rsqrtf(var + LN_EPS) * lng[j] + lnb[j];
}

__global__ void bcast_kernel(const float* __restrict__ init0, const float* __restrict__ embed0,
                             unsigned short* __restrict__ hb, float* __restrict__ cb,
                             unsigned short* __restrict__ embed,
                             long long total, long long NH)
{
    long long idx = (long long)blockIdx.x * blockDim.x + threadIdx.x;
    if (idx >= total) return;
    int b = (int)(idx / NH);
    int j = (int)(idx & 127);
    hb[idx] = f2bf(init0[b * 128 + j]);
    embed[idx] = f2bf(embed0[b * 128 + j]);
    cb[idx] = 0.f;
}

__global__ void cast_kernel(const float* __restrict__ x, unsigned short* __restrict__ xb,
                            long long n4)
{
    long long i = ((long long)blockIdx.x * blockDim.x + threadIdx.x);
    if (i >= n4) return;
    float4 v = *(const float4*)(x + i * 4);
    ushort4 o;
    o.x = f2bf(v.x); o.y = f2bf(v.y); o.z = f2bf(v.z); o.w = f2bf(v.w);
    *(ushort4*)&xb[i * 4] = o;
}

struct CastArgs {
    const float* src[7];
    unsigned short* dst[7];
    int n[7];
};

__global__ void castw_kernel(CastArgs a)
{
    int rg = blockIdx.y;
    int i = (blockIdx.x * blockDim.x + threadIdx.x) * 4;
    if (i < a.n[rg]) {
        float4 v = *(const float4*)(a.src[rg] + i);
        ushort4 o;
        o.x = f2bf(v.x); o.y = f2bf(v.y); o.z = f2bf(v.z); o.w = f2bf(v.w);
        *(ushort4*)(a.dst[rg] + i) = o;
    }
}

__global__ void sigmoid_kernel(const float* __restrict__ logit, float* __restrict__ out, int B)
{
    int b = threadIdx.x;
    if (b < B) out[b] = 1.f / (1.f + __expf(-logit[b]));
}

// ---------------- launch ---------------------------------------------------------------
extern "C" void kernel_launch(void* const* d_in, const int* in_sizes, int n_in,
                              void* d_out, int out_size, void* d_ws, size_t ws_size,
                              hipStream_t stream)
{
    const float* x    = (const float*)d_in[0];
    const float* kk   = (const float*)d_in[1];
    const float* nn   = (const float*)d_in[2];
    const float* mask = (const float*)d_in[3];
    const float* iw1  = (const float*)d_in[4];
    const float* ib1  = (const float*)d_in[5];
    const float* iw2  = (const float*)d_in[6];
    const float* ib2  = (const float*)d_in[7];
    const float* iw3  = (const float*)d_in[8];
    const float* ib3  = (const float*)d_in[9];
    const float* mw1  = (const float*)d_in[10];
    const float* mb1  = (const float*)d_in[11];
    const float* mw2  = (const float*)d_in[12];
    const float* mb2  = (const float*)d_in[13];
    const float* mw3  = (const float*)d_in[14];
    const float* mb3  = (const float*)d_in[15];
    const float* wih  = (const float*)d_in[16];
    const float* whh  = (const float*)d_in[17];
    const float* bih  = (const float*)d_in[18];
    const float* bhh  = (const float*)d_in[19];
    const float* lng  = (const float*)d_in[20];
    const float* lnb  = (const float*)d_in[21];
    const float* vw1  = (const float*)d_in[22];
    const float* vb1  = (const float*)d_in[23];
    const float* vw2  = (const float*)d_in[24];
    const float* vb2  = (const float*)d_in[25];
    const float* vw3  = (const float*)d_in[26];
    const float* vb3  = (const float*)d_in[27];
    float* out = (float*)d_out;

    const int B = in_sizes[1];        // 4
    const int H = in_sizes[5];        // 128
    const int N = in_sizes[3] / B;    // 4096
    const long long NH  = (long long)N * H;
    const long long BNH = (long long)B * NH;
    const int M = B * N;

    char* p = (char*)d_ws;
    auto alloc = [&](long long bytes) {
        char* q = p; p += (bytes + 255) & ~255LL; return q;
    };
    float*          cb     = (float*)alloc(BNH * 4);
    unsigned short* embed  = (unsigned short*)alloc(BNH * 2);
    unsigned short* hb     = (unsigned short*)alloc(BNH * 2);
    unsigned short* msg    = (unsigned short*)alloc(BNH * 2);
    unsigned short* m_t    = (unsigned short*)alloc(BNH * 2);
    float*          init0  = (float*)alloc((long long)B * H * 4);
    float*          embed0 = (float*)alloc((long long)B * H * 4);
    float*          logit  = (float*)alloc((long long)B * 4);
    unsigned short* wb_m1  = (unsigned short*)alloc((long long)H * H * 2);
    unsigned short* wb_m2  = (unsigned short*)alloc((long long)H * H * 2);
    unsigned short* wb_m3  = (unsigned short*)alloc((long long)H * H * 2);
    unsigned short* wb_ih  = (unsigned short*)alloc(4LL * H * H * 2);
    unsigned short* wb_hh  = (unsigned short*)alloc(4LL * H * H * 2);
    unsigned short* wb_v1  = (unsigned short*)alloc((long long)H * H * 2);
    unsigned short* wb_v2  = (unsigned short*)alloc((long long)H * H * 2);
    unsigned short* x_bf   = (unsigned short*)alloc(2LL * B * N * N);
    const bool use_xb = ((long long)(p - (char*)d_ws) <= (long long)ws_size);

    init_kernel<<<B, H, 0, stream>>>(kk, nn, iw1, ib1, iw2, ib2, iw3, ib3, lng, lnb,
                                     init0, embed0, logit, H);
    {
        long long nb = (BNH + 255) / 256;
        bcast_kernel<<<dim3((unsigned)nb), 256, 0, stream>>>(init0, embed0, hb, cb, embed, BNH, NH);
    }
    {
        CastArgs ca;
        ca.src[0] = mw1; ca.dst[0] = wb_m1; ca.n[0] = H * H;
        ca.src[1] = mw2; ca.dst[1] = wb_m2; ca.n[1] = H * H;
        ca.src[2] = mw3; ca.dst[2] = wb_m3; ca.n[2] = H * H;
        ca.src[3] = wih; ca.dst[3] = wb_ih; ca.n[3] = 4 * H * H;
        ca.src[4] = whh; ca.dst[4] = wb_hh; ca.n[4] = 4 * H * H;
        ca.src[5] = vw1; ca.dst[5] = wb_v1; ca.n[5] = H * H;
        ca.src[6] = vw2; ca.dst[6] = wb_v2; ca.n[6] = H * H;
        castw_kernel<<<dim3(64, 7), 256, 0, stream>>>(ca);
    }
    if (use_xb) {
        long long n4 = (long long)B * N * N / 4;
        cast_kernel<<<dim3((unsigned)((n4 + 255) / 256)), 256, 0, stream>>>(x, x_bf, n4);
    }

    dim3 gridRow(M / 64);
    dim3 gridAgg(N / 16, B);

    for (int it = 0; it < 8; ++it) {
        msg_mlp_kernel<<<gridRow, 256, 0, stream>>>(embed, wb_m1, mb1, wb_m2, mb2,
                                                    wb_m3, mb3, m_t, N);
        if (use_xb)
            agg_kernel<true><<<gridAgg, 256, 0, stream>>>(nullptr, x_bf, m_t, msg, N);
        else
            agg_kernel<false><<<gridAgg, 256, 0, stream>>>(x, nullptr, m_t, msg, N);
        gates_lstm_kernel<<<gridRow, 256, 0, stream>>>(msg, hb, cb, wb_ih, wb_hh,
                                                       bih, bhh, lng, lnb, embed);
    }

    vote_mlp_kernel<<<gridRow, 256, 0, stream>>>(embed, wb_v1, vb1, wb_v2, vb2,
                                                 vw3, vb3, mask, logit, N);
    sigmoid_kernel<<<1, 64, 0, stream>>>(logit, out, B);
}

// Round 4
// 1947.098 us; speedup vs baseline: 2.0849x; 1.0429x over previous
//
#include <hip/hip_runtime.h>
#include <cstddef>

#define LN_EPS 1e-5f

typedef __attribute__((ext_vector_type(8))) short bf16x8;
typedef __attribute__((ext_vector_type(4))) float f32x4;

__device__ __forceinline__ unsigned short f2bf(float f) {
    unsigned u = __float_as_uint(f);
    u += 0x7FFFu + ((u >> 16) & 1u);   // round-to-nearest-even
    return (unsigned short)(u >> 16);
}
__device__ __forceinline__ float sigf(float x) { return 1.f / (1.f + __expf(-x)); }

// One K=128 -> 128-col MFMA layer. W is bf16 [128 out][128 in] (torch layout).
__device__ __forceinline__ void layer128(const unsigned short* __restrict__ W,
                                         const bf16x8 a[4], f32x4 acc[8],
                                         int lr, int lq)
{
#pragma unroll
    for (int s = 0; s < 4; ++s) {
#pragma unroll
        for (int tn = 0; tn < 8; ++tn) {
            bf16x8 b = *(const bf16x8*)(W + (tn * 16 + lr) * 128 + s * 32 + lq * 8);
            acc[tn] = __builtin_amdgcn_mfma_f32_16x16x32_bf16(a[s], b, acc[tn], 0, 0, 0);
        }
    }
}

// ---------------- fused msg MLP: embed(bf16) -> 3 layers -> m_t (bf16, [B][H][N]) ----
__global__ __launch_bounds__(256)
void msg_mlp_kernel(const unsigned short* __restrict__ embed,
                    const unsigned short* __restrict__ w1, const float* __restrict__ b1,
                    const unsigned short* __restrict__ w2, const float* __restrict__ b2,
                    const unsigned short* __restrict__ w3, const float* __restrict__ b3,
                    unsigned short* __restrict__ m_t, int N)
{
    __shared__ unsigned short sact[4][16][136];   // per-wave staging
    const int lane = threadIdx.x & 63, wave = threadIdx.x >> 6;
    const int lr = lane & 15, lq = lane >> 4;
    const int r0 = (blockIdx.x * 4 + wave) * 16;

    bf16x8 a[4];
    f32x4 acc[8];

#pragma unroll
    for (int s = 0; s < 4; ++s)
        a[s] = *(const bf16x8*)(embed + (long long)(r0 + lr) * 128 + s * 32 + lq * 8);
#pragma unroll
    for (int tn = 0; tn < 8; ++tn) acc[tn] = (f32x4)(0.f);
    layer128(w1, a, acc, lr, lq);

#pragma unroll
    for (int tn = 0; tn < 8; ++tn) {
        float bb = b1[tn * 16 + lr];
#pragma unroll
        for (int r = 0; r < 4; ++r) {
            float v = acc[tn][r] + bb; v = v > 0.f ? v : 0.f;
            sact[wave][lq * 4 + r][tn * 16 + lr] = f2bf(v);
        }
    }
    __syncthreads();
#pragma unroll
    for (int s = 0; s < 4; ++s)
        a[s] = *(const bf16x8*)&sact[wave][lr][s * 32 + lq * 8];
#pragma unroll
    for (int tn = 0; tn < 8; ++tn) acc[tn] = (f32x4)(0.f);
    layer128(w2, a, acc, lr, lq);

#pragma unroll
    for (int tn = 0; tn < 8; ++tn) {
        float bb = b2[tn * 16 + lr];
#pragma unroll
        for (int r = 0; r < 4; ++r) {
            float v = acc[tn][r] + bb; v = v > 0.f ? v : 0.f;
            sact[wave][lq * 4 + r][tn * 16 + lr] = f2bf(v);
        }
    }
    __syncthreads();
#pragma unroll
    for (int s = 0; s < 4; ++s)
        a[s] = *(const bf16x8*)&sact[wave][lr][s * 32 + lq * 8];
#pragma unroll
    for (int tn = 0; tn < 8; ++tn) acc[tn] = (f32x4)(0.f);
    layer128(w3, a, acc, lr, lq);

    const int batch = r0 / N;                 // blocks never straddle batches
    const int rin0 = r0 - batch * N + lq * 4;
#pragma unroll
    for (int tn = 0; tn < 8; ++tn) {
        float bb = b3[tn * 16 + lr];
        ushort4 o;
        o.x = f2bf(acc[tn][0] + bb); o.y = f2bf(acc[tn][1] + bb);
        o.z = f2bf(acc[tn][2] + bb); o.w = f2bf(acc[tn][3] + bb);
        *(ushort4*)(m_t + ((long long)(batch * 128 + tn * 16 + lr)) * N + rin0) = o;
    }
}

// ---------------- aggregation: msg[b] = x[b] @ m[b]; K-split over 4 waves --------------
template<bool XB>
__global__ __launch_bounds__(256)
void agg_kernel(const float* __restrict__ xf, const unsigned short* __restrict__ xb,
                const unsigned short* __restrict__ mt, unsigned short* __restrict__ msgout,
                int N)
{
    __shared__ float sacc[4][16][132];
    const int lane = threadIdx.x & 63, wave = threadIdx.x >> 6;
    const int lr = lane & 15, lq = lane >> 4;
    const int batch = blockIdx.y;
    const int rowBase = blockIdx.x * 16;
    const int kBase = wave * (N >> 2);
    const int kIters = N >> 7;                 // (N/4)/32

    const long long xoff = (long long)batch * N * N + (long long)(rowBase + lr) * N + kBase + lq * 8;
    const unsigned short* ab = xb + xoff;
    const float*          af = xf + xoff;
    const long long bbase = (long long)batch * 128 * N + (long long)lr * N + kBase + lq * 8;

    f32x4 acc[8];
#pragma unroll
    for (int tn = 0; tn < 8; ++tn) acc[tn] = (f32x4)(0.f);

    auto loadA = [&](int k) -> bf16x8 {
        if (XB) {
            return *(const bf16x8*)(ab + k);
        } else {
            float4 lo = *(const float4*)(af + k);
            float4 hi = *(const float4*)(af + k + 4);
            bf16x8 r;
            r[0] = (short)f2bf(lo.x); r[1] = (short)f2bf(lo.y);
            r[2] = (short)f2bf(lo.z); r[3] = (short)f2bf(lo.w);
            r[4] = (short)f2bf(hi.x); r[5] = (short)f2bf(hi.y);
            r[6] = (short)f2bf(hi.z); r[7] = (short)f2bf(hi.w);
            return r;
        }
    };

    bf16x8 a0 = loadA(0);
    bf16x8 b0[8], b1[8];
#pragma unroll
    for (int tn = 0; tn < 8; ++tn)
        b0[tn] = *(const bf16x8*)(mt + bbase + (long long)tn * 16 * N);

    for (int it = 1; it < kIters; ++it) {
        const int k = it * 32;
        bf16x8 a1 = loadA(k);
#pragma unroll
        for (int tn = 0; tn < 8; ++tn)
            b1[tn] = *(const bf16x8*)(mt + bbase + (long long)tn * 16 * N + k);
#pragma unroll
        for (int tn = 0; tn < 8; ++tn)
            acc[tn] = __builtin_amdgcn_mfma_f32_16x16x32_bf16(a0, b0[tn], acc[tn], 0, 0, 0);
        a0 = a1;
#pragma unroll
        for (int tn = 0; tn < 8; ++tn) b0[tn] = b1[tn];
    }
#pragma unroll
    for (int tn = 0; tn < 8; ++tn)
        acc[tn] = __builtin_amdgcn_mfma_f32_16x16x32_bf16(a0, b0[tn], acc[tn], 0, 0, 0);

#pragma unroll
    for (int tn = 0; tn < 8; ++tn)
#pragma unroll
        for (int r = 0; r < 4; ++r)
            sacc[wave][lq * 4 + r][tn * 16 + lr] = acc[tn][r];
    __syncthreads();
    {
        const int t = threadIdx.x;
        const int row = t >> 4, cb2 = (t & 15) * 8;
        unsigned short o[8];
#pragma unroll
        for (int j = 0; j < 8; ++j) {
            float v = sacc[0][row][cb2 + j] + sacc[1][row][cb2 + j]
                    + sacc[2][row][cb2 + j] + sacc[3][row][cb2 + j];
            o[j] = f2bf(v);
        }
        unsigned short* dst = msgout + (long long)(batch * N + rowBase + row) * 128 + cb2;
        *(ushort4*)dst = *(ushort4*)&o[0];
        *(ushort4*)(dst + 4) = *(ushort4*)&o[4];
    }
}

// ------- fused dual-GEMM gates + LSTM + LayerNorm; cols split across waves -------------
// block = 16 rows; wave w owns cols [w*32, w*32+32) of all 4 gates -> acc[8] (32 VGPRs).
__global__ __launch_bounds__(256)
void gates_lstm_kernel(const unsigned short* __restrict__ msg,
                       unsigned short* hb, float* cb,
                       const unsigned short* __restrict__ wih,
                       const unsigned short* __restrict__ whh,
                       const float* __restrict__ bih, const float* __restrict__ bhh,
                       const float* __restrict__ lng, const float* __restrict__ lnb,
                       unsigned short* __restrict__ embed_out)
{
    __shared__ float sred[4][16][2];
    const int lane = threadIdx.x & 63, wave = threadIdx.x >> 6;
    const int lr = lane & 15, lq = lane >> 4;
    const int r0 = blockIdx.x * 16;

    f32x4 acc[8];    // tt = gate*2 + half
#pragma unroll
    for (int t = 0; t < 8; ++t) acc[t] = (f32x4)(0.f);

    bf16x8 a[4];
#pragma unroll
    for (int s = 0; s < 4; ++s)
        a[s] = *(const bf16x8*)(msg + (long long)(r0 + lr) * 128 + s * 32 + lq * 8);
#pragma unroll
    for (int s = 0; s < 4; ++s)
#pragma unroll
        for (int tt = 0; tt < 8; ++tt) {
            const int brow = (tt >> 1) * 128 + wave * 32 + (tt & 1) * 16 + lr;
            bf16x8 b = *(const bf16x8*)(wih + brow * 128 + s * 32 + lq * 8);
            acc[tt] = __builtin_amdgcn_mfma_f32_16x16x32_bf16(a[s], b, acc[tt], 0, 0, 0);
        }
#pragma unroll
    for (int s = 0; s < 4; ++s)
        a[s] = *(const bf16x8*)((const unsigned short*)hb + (long long)(r0 + lr) * 128 + s * 32 + lq * 8);
#pragma unroll
    for (int s = 0; s < 4; ++s)
#pragma unroll
        for (int tt = 0; tt < 8; ++tt) {
            const int brow = (tt >> 1) * 128 + wave * 32 + (tt & 1) * 16 + lr;
            bf16x8 b = *(const bf16x8*)(whh + brow * 128 + s * 32 + lq * 8);
            acc[tt] = __builtin_amdgcn_mfma_f32_16x16x32_bf16(a[s], b, acc[tt], 0, 0, 0);
        }

    // LSTM elementwise. col = wave*32 + half*16 + lr; rows = lq*4 + r.
    float hn[2][4];
    float4* cw = (float4*)cb;   // private tiled layout: [(block*8 + wave*2 + half)*64 + lane]
#pragma unroll
    for (int half = 0; half < 2; ++half) {
        const int col = wave * 32 + half * 16 + lr;
        const float bi  = bih[col]       + bhh[col];
        const float bf_ = bih[col + 128] + bhh[col + 128];
        const float bg  = bih[col + 256] + bhh[col + 256];
        const float bo  = bih[col + 384] + bhh[col + 384];
        const long long cidx = ((long long)blockIdx.x * 8 + wave * 2 + half) * 64 + lane;
        float4 cold = cw[cidx];
        float co[4] = {cold.x, cold.y, cold.z, cold.w};
        float cn[4];
#pragma unroll
        for (int r = 0; r < 4; ++r) {
            float iv = acc[0 + half][r] + bi;
            float fv = acc[2 + half][r] + bf_;
            float gv = acc[4 + half][r] + bg;
            float ov = acc[6 + half][r] + bo;
            float cc = sigf(fv) * co[r] + sigf(iv) * tanhf(gv);
            cn[r] = cc;
            hn[half][r] = sigf(ov) * tanhf(cc);
        }
        float4 cnew = {cn[0], cn[1], cn[2], cn[3]};
        cw[cidx] = cnew;
    }

    // LayerNorm: per-row (lq*4+r) sums over this wave's 32 cols, then LDS across waves.
    float ps1[4], ps2[4];
#pragma unroll
    for (int r = 0; r < 4; ++r) {
        float s1 = hn[0][r] + hn[1][r];
        float s2 = hn[0][r] * hn[0][r] + hn[1][r] * hn[1][r];
#pragma unroll
        for (int m = 1; m <= 8; m <<= 1) {
            s1 += __shfl_xor(s1, m);
            s2 += __shfl_xor(s2, m);
        }
        ps1[r] = s1; ps2[r] = s2;
    }
    if (lr == 0) {
#pragma unroll
        for (int r = 0; r < 4; ++r) {
            sred[wave][lq * 4 + r][0] = ps1[r];
            sred[wave][lq * 4 + r][1] = ps2[r];
        }
    }
    __syncthreads();

#pragma unroll
    for (int half = 0; half < 2; ++half) {
        const int col = wave * 32 + half * 16 + lr;
        const float g = lng[col], bb = lnb[col];
#pragma unroll
        for (int r = 0; r < 4; ++r) {
            const int row = lq * 4 + r;
            float S1 = sred[0][row][0] + sred[1][row][0] + sred[2][row][0] + sred[3][row][0];
            float S2 = sred[0][row][1] + sred[1][row][1] + sred[2][row][1] + sred[3][row][1];
            float mean = S1 * (1.f / 128.f);
            float var  = S2 * (1.f / 128.f) - mean * mean;
            float rs = rsqrtf(var + LN_EPS);
            long long off = (long long)(r0 + row) * 128 + col;
            hb[off] = f2bf(hn[half][r]);
            embed_out[off] = f2bf((hn[half][r] - mean) * rs * g + bb);
        }
    }
}

// ---------------- fused vote MLP (2 layers) + layer3 dot + masked sum ------------------
__global__ __launch_bounds__(256)
void vote_mlp_kernel(const unsigned short* __restrict__ embed,
                     const unsigned short* __restrict__ w1, const float* __restrict__ b1,
                     const unsigned short* __restrict__ w2, const float* __restrict__ b2,
                     const float* __restrict__ w3, const float* __restrict__ b3p,
                     const float* __restrict__ mask, float* __restrict__ logit, int N)
{
    __shared__ unsigned short sact[4][16][136];
    const int lane = threadIdx.x & 63, wave = threadIdx.x >> 6;
    const int lr = lane & 15, lq = lane >> 4;
    const int r0 = (blockIdx.x * 4 + wave) * 16;

    bf16x8 a[4];
    f32x4 acc[8];
#pragma unroll
    for (int s = 0; s < 4; ++s)
        a[s] = *(const bf16x8*)(embed + (long long)(r0 + lr) * 128 + s * 32 + lq * 8);
#pragma unroll
    for (int tn = 0; tn < 8; ++tn) acc[tn] = (f32x4)(0.f);
    layer128(w1, a, acc, lr, lq);

#pragma unroll
    for (int tn = 0; tn < 8; ++tn) {
        float bb = b1[tn * 16 + lr];
#pragma unroll
        for (int r = 0; r < 4; ++r) {
            float v = acc[tn][r] + bb; v = v > 0.f ? v : 0.f;
            sact[wave][lq * 4 + r][tn * 16 + lr] = f2bf(v);
        }
    }
    __syncthreads();
#pragma unroll
    for (int s = 0; s < 4; ++s)
        a[s] = *(const bf16x8*)&sact[wave][lr][s * 32 + lq * 8];
#pragma unroll
    for (int tn = 0; tn < 8; ++tn) acc[tn] = (f32x4)(0.f);
    layer128(w2, a, acc, lr, lq);

    float dot[4] = {0.f, 0.f, 0.f, 0.f};
#pragma unroll
    for (int tn = 0; tn < 8; ++tn) {
        const int col = tn * 16 + lr;
        const float bb = b2[col], w3c = w3[col];
#pragma unroll
        for (int r = 0; r < 4; ++r) {
            float v = acc[tn][r] + bb; v = v > 0.f ? v : 0.f;
            dot[r] += v * w3c;
        }
    }
#pragma unroll
    for (int r = 0; r < 4; ++r)
#pragma unroll
        for (int m = 1; m <= 8; m <<= 1) dot[r] += __shfl_xor(dot[r], m);

    const int batch = r0 / N;
    const float b3 = b3p[0];
    const int base = r0 + lq * 4;
    float wsum = mask[base + 0] * (dot[0] + b3) + mask[base + 1] * (dot[1] + b3)
               + mask[base + 2] * (dot[2] + b3) + mask[base + 3] * (dot[3] + b3);
    float t = (lr == 0) ? wsum : 0.f;
    t += __shfl_xor(t, 16);
    t += __shfl_xor(t, 32);
    if (lane == 0) atomicAdd(&logit[batch], t);
}

// ---------------- small kernels --------------------------------------------------------
__global__ __launch_bounds__(128)
void init_kernel(const float* __restrict__ kk, const float* __restrict__ nn,
                 const float* __restrict__ w1, const float* __restrict__ b1,
                 const float* __restrict__ w2, const float* __restrict__ b2,
                 const float* __restrict__ w3, const float* __restrict__ b3,
                 const float* __restrict__ lng, const float* __restrict__ lnb,
                 float* __restrict__ init0, float* __restrict__ embed0,
                 float* __restrict__ logit, int H)
{
    int b = blockIdx.x, j = threadIdx.x;
    __shared__ float s1[128];
    __shared__ float s2[128];
    __shared__ float red[128];
    if (j == 0) logit[b] = 0.f;
    float kv = kk[b], nv = nn[b];
    float h1 = w1[j * 2 + 0] * kv + w1[j * 2 + 1] * nv + b1[j];
    h1 = h1 > 0.f ? h1 : 0.f;
    s1[j] = h1; __syncthreads();
    float h2 = b2[j];
    for (int q = 0; q < H; ++q) h2 += w2[j * H + q] * s1[q];
    h2 = h2 > 0.f ? h2 : 0.f;
    s2[j] = h2; __syncthreads();
    float o = b3[j];
    for (int q = 0; q < H; ++q) o += w3[j * H + q] * s2[q];
    init0[b * H + j] = o;

    red[j] = o; __syncthreads();
    for (int s = 64; s > 0; s >>= 1) { if (j < s) red[j] += red[j + s]; __syncthreads(); }
    float mu = red[0] / (float)H;
    __syncthreads();
    float d = o - mu;
    red[j] = d * d; __syncthreads();
    for (int s = 64; s > 0; s >>= 1) { if (j < s) red[j] += red[j + s]; __syncthreads(); }
    float var = red[0] / (float)H;
    embed0[b * H + j] = d * rsqrtf(var + LN_EPS) * lng[j] + lnb[j];
}

__global__ void bcast_kernel(const float* __restrict__ init0, const float* __restrict__ embed0,
                             unsigned short* __restrict__ hb, float* __restrict__ cb,
                             unsigned short* __restrict__ embed,
                             long long total, long long NH)
{
    long long idx = (long long)blockIdx.x * blockDim.x + threadIdx.x;
    if (idx >= total) return;
    int b = (int)(idx / NH);
    int j = (int)(idx & 127);
    hb[idx] = f2bf(init0[b * 128 + j]);
    embed[idx] = f2bf(embed0[b * 128 + j]);
    cb[idx] = 0.f;
}

__global__ void cast_kernel(const float* __restrict__ x, unsigned short* __restrict__ xb,
                            long long n4)
{
    long long i = ((long long)blockIdx.x * blockDim.x + threadIdx.x);
    if (i >= n4) return;
    float4 v = *(const float4*)(x + i * 4);
    ushort4 o;
    o.x = f2bf(v.x); o.y = f2bf(v.y); o.z = f2bf(v.z); o.w = f2bf(v.w);
    *(ushort4*)&xb[i * 4] = o;
}

struct CastArgs {
    const float* src[7];
    unsigned short* dst[7];
    int n[7];
};

__global__ void castw_kernel(CastArgs a)
{
    int rg = blockIdx.y;
    int i = (blockIdx.x * blockDim.x + threadIdx.x) * 4;
    if (i < a.n[rg]) {
        float4 v = *(const float4*)(a.src[rg] + i);
        ushort4 o;
        o.x = f2bf(v.x); o.y = f2bf(v.y); o.z = f2bf(v.z); o.w = f2bf(v.w);
        *(ushort4*)(a.dst[rg] + i) = o;
    }
}

__global__ void sigmoid_kernel(const float* __restrict__ logit, float* __restrict__ out, int B)
{
    int b = threadIdx.x;
    if (b < B) out[b] = 1.f / (1.f + __expf(-logit[b]));
}

// ---------------- launch ---------------------------------------------------------------
extern "C" void kernel_launch(void* const* d_in, const int* in_sizes, int n_in,
                              void* d_out, int out_size, void* d_ws, size_t ws_size,
                              hipStream_t stream)
{
    const float* x    = (const float*)d_in[0];
    const float* kk   = (const float*)d_in[1];
    const float* nn   = (const float*)d_in[2];
    const float* mask = (const float*)d_in[3];
    const float* iw1  = (const float*)d_in[4];
    const float* ib1  = (const float*)d_in[5];
    const float* iw2  = (const float*)d_in[6];
    const float* ib2  = (const float*)d_in[7];
    const float* iw3  = (const float*)d_in[8];
    const float* ib3  = (const float*)d_in[9];
    const float* mw1  = (const float*)d_in[10];
    const float* mb1  = (const float*)d_in[11];
    const float* mw2  = (const float*)d_in[12];
    const float* mb2  = (const float*)d_in[13];
    const float* mw3  = (const float*)d_in[14];
    const float* mb3  = (const float*)d_in[15];
    const float* wih  = (const float*)d_in[16];
    const float* whh  = (const float*)d_in[17];
    const float* bih  = (const float*)d_in[18];
    const float* bhh  = (const float*)d_in[19];
    const float* lng  = (const float*)d_in[20];
    const float* lnb  = (const float*)d_in[21];
    const float* vw1  = (const float*)d_in[22];
    const float* vb1  = (const float*)d_in[23];
    const float* vw2  = (const float*)d_in[24];
    const float* vb2  = (const float*)d_in[25];
    const float* vw3  = (const float*)d_in[26];
    const float* vb3  = (const float*)d_in[27];
    float* out = (float*)d_out;

    const int B = in_sizes[1];        // 4
    const int H = in_sizes[5];        // 128
    const int N = in_sizes[3] / B;    // 4096
    const long long NH  = (long long)N * H;
    const long long BNH = (long long)B * NH;
    const int M = B * N;

    char* p = (char*)d_ws;
    auto alloc = [&](long long bytes) {
        char* q = p; p += (bytes + 255) & ~255LL; return q;
    };
    float*          cb     = (float*)alloc(BNH * 4);
    unsigned short* embed  = (unsigned short*)alloc(BNH * 2);
    unsigned short* hb     = (unsigned short*)alloc(BNH * 2);
    unsigned short* msg    = (unsigned short*)alloc(BNH * 2);
    unsigned short* m_t    = (unsigned short*)alloc(BNH * 2);
    float*          init0  = (float*)alloc((long long)B * H * 4);
    float*          embed0 = (float*)alloc((long long)B * H * 4);
    float*          logit  = (float*)alloc((long long)B * 4);
    unsigned short* wb_m1  = (unsigned short*)alloc((long long)H * H * 2);
    unsigned short* wb_m2  = (unsigned short*)alloc((long long)H * H * 2);
    unsigned short* wb_m3  = (unsigned short*)alloc((long long)H * H * 2);
    unsigned short* wb_ih  = (unsigned short*)alloc(4LL * H * H * 2);
    unsigned short* wb_hh  = (unsigned short*)alloc(4LL * H * H * 2);
    unsigned short* wb_v1  = (unsigned short*)alloc((long long)H * H * 2);
    unsigned short* wb_v2  = (unsigned short*)alloc((long long)H * H * 2);
    unsigned short* x_bf   = (unsigned short*)alloc(2LL * B * N * N);
    const bool use_xb = ((long long)(p - (char*)d_ws) <= (long long)ws_size);

    init_kernel<<<B, H, 0, stream>>>(kk, nn, iw1, ib1, iw2, ib2, iw3, ib3, lng, lnb,
                                     init0, embed0, logit, H);
    {
        long long nb = (BNH + 255) / 256;
        bcast_kernel<<<dim3((unsigned)nb), 256, 0, stream>>>(init0, embed0, hb, cb, embed, BNH, NH);
    }
    {
        CastArgs ca;
        ca.src[0] = mw1; ca.dst[0] = wb_m1; ca.n[0] = H * H;
        ca.src[1] = mw2; ca.dst[1] = wb_m2; ca.n[1] = H * H;
        ca.src[2] = mw3; ca.dst[2] = wb_m3; ca.n[2] = H * H;
        ca.src[3] = wih; ca.dst[3] = wb_ih; ca.n[3] = 4 * H * H;
        ca.src[4] = whh; ca.dst[4] = wb_hh; ca.n[4] = 4 * H * H;
        ca.src[5] = vw1; ca.dst[5] = wb_v1; ca.n[5] = H * H;
        ca.src[6] = vw2; ca.dst[6] = wb_v2; ca.n[6] = H * H;
        castw_kernel<<<dim3(64, 7), 256, 0, stream>>>(ca);
    }
    if (use_xb) {
        long long n4 = (long long)B * N * N / 4;
        cast_kernel<<<dim3((unsigned)((n4 + 255) / 256)), 256, 0, stream>>>(x, x_bf, n4);
    }

    dim3 gridRow(M / 64);
    dim3 gridRow16(M / 16);
    dim3 gridAgg(N / 16, B);

    for (int it = 0; it < 8; ++it) {
        msg_mlp_kernel<<<gridRow, 256, 0, stream>>>(embed, wb_m1, mb1, wb_m2, mb2,
                                                    wb_m3, mb3, m_t, N);
        if (use_xb)
            agg_kernel<true><<<gridAgg, 256, 0, stream>>>(nullptr, x_bf, m_t, msg, N);
        else
            agg_kernel<false><<<gridAgg, 256, 0, stream>>>(x, nullptr, m_t, msg, N);
        gates_lstm_kernel<<<gridRow16, 256, 0, stream>>>(msg, hb, cb, wb_ih, wb_hh,
                                                         bih, bhh, lng, lnb, embed);
    }

    vote_mlp_kernel<<<gridRow, 256, 0, stream>>>(embed, wb_v1, vb1, wb_v2, vb2,
                                                 vw3, vb3, mask, logit, N);
    sigmoid_kernel<<<1, 64, 0, stream>>>(logit, out, B);
}

// Round 5
// 1265.079 us; speedup vs baseline: 3.2089x; 1.5391x over previous
//
#include <hip/hip_runtime.h>
#include <cstddef>
#include <cstdint>

#define LN_EPS 1e-5f

typedef __attribute__((ext_vector_type(8))) short bf16x8;
typedef __attribute__((ext_vector_type(4))) float f32x4;

__device__ __forceinline__ unsigned short f2bf(float f) {
    unsigned u = __float_as_uint(f);
    u += 0x7FFFu + ((u >> 16) & 1u);   // round-to-nearest-even
    return (unsigned short)(u >> 16);
}
__device__ __forceinline__ float sigf(float x) { return 1.f / (1.f + __expf(-x)); }

// async global->LDS, 16B per lane. lds dest = wave-uniform base + lane*16.
__device__ __forceinline__ void gload_lds16(const void* g, void* l) {
    __builtin_amdgcn_global_load_lds(
        (const __attribute__((address_space(1))) unsigned int*)(unsigned long long)(uintptr_t)g,
        (__attribute__((address_space(3))) unsigned int*)(unsigned int)(uintptr_t)l,
        16, 0, 0);
}

// One K=128 -> 128-col MFMA layer. W is bf16 [128 out][128 in] (torch layout).
__device__ __forceinline__ void layer128(const unsigned short* __restrict__ W,
                                         const bf16x8 a[4], f32x4 acc[8],
                                         int lr, int lq)
{
#pragma unroll
    for (int s = 0; s < 4; ++s) {
#pragma unroll
        for (int tn = 0; tn < 8; ++tn) {
            bf16x8 b = *(const bf16x8*)(W + (tn * 16 + lr) * 128 + s * 32 + lq * 8);
            acc[tn] = __builtin_amdgcn_mfma_f32_16x16x32_bf16(a[s], b, acc[tn], 0, 0, 0);
        }
    }
}

// ---------------- fused msg MLP: embed(bf16) -> 3 layers -> m_t (bf16, [B][H][N]) ----
__global__ __launch_bounds__(256)
void msg_mlp_kernel(const unsigned short* __restrict__ embed,
                    const unsigned short* __restrict__ w1, const float* __restrict__ b1,
                    const unsigned short* __restrict__ w2, const float* __restrict__ b2,
                    const unsigned short* __restrict__ w3, const float* __restrict__ b3,
                    unsigned short* __restrict__ m_t, int N)
{
    __shared__ unsigned short sact[4][16][136];
    const int lane = threadIdx.x & 63, wave = threadIdx.x >> 6;
    const int lr = lane & 15, lq = lane >> 4;
    const int r0 = (blockIdx.x * 4 + wave) * 16;

    bf16x8 a[4];
    f32x4 acc[8];

#pragma unroll
    for (int s = 0; s < 4; ++s)
        a[s] = *(const bf16x8*)(embed + (long long)(r0 + lr) * 128 + s * 32 + lq * 8);
#pragma unroll
    for (int tn = 0; tn < 8; ++tn) acc[tn] = (f32x4)(0.f);
    layer128(w1, a, acc, lr, lq);

#pragma unroll
    for (int tn = 0; tn < 8; ++tn) {
        float bb = b1[tn * 16 + lr];
#pragma unroll
        for (int r = 0; r < 4; ++r) {
            float v = acc[tn][r] + bb; v = v > 0.f ? v : 0.f;
            sact[wave][lq * 4 + r][tn * 16 + lr] = f2bf(v);
        }
    }
    __syncthreads();
#pragma unroll
    for (int s = 0; s < 4; ++s)
        a[s] = *(const bf16x8*)&sact[wave][lr][s * 32 + lq * 8];
#pragma unroll
    for (int tn = 0; tn < 8; ++tn) acc[tn] = (f32x4)(0.f);
    layer128(w2, a, acc, lr, lq);

#pragma unroll
    for (int tn = 0; tn < 8; ++tn) {
        float bb = b2[tn * 16 + lr];
#pragma unroll
        for (int r = 0; r < 4; ++r) {
            float v = acc[tn][r] + bb; v = v > 0.f ? v : 0.f;
            sact[wave][lq * 4 + r][tn * 16 + lr] = f2bf(v);
        }
    }
    __syncthreads();
#pragma unroll
    for (int s = 0; s < 4; ++s)
        a[s] = *(const bf16x8*)&sact[wave][lr][s * 32 + lq * 8];
#pragma unroll
    for (int tn = 0; tn < 8; ++tn) acc[tn] = (f32x4)(0.f);
    layer128(w3, a, acc, lr, lq);

    const int batch = r0 / N;
    const int rin0 = r0 - batch * N + lq * 4;
#pragma unroll
    for (int tn = 0; tn < 8; ++tn) {
        float bb = b3[tn * 16 + lr];
        ushort4 o;
        o.x = f2bf(acc[tn][0] + bb); o.y = f2bf(acc[tn][1] + bb);
        o.z = f2bf(acc[tn][2] + bb); o.w = f2bf(acc[tn][3] + bb);
        *(ushort4*)(m_t + ((long long)(batch * 128 + tn * 16 + lr)) * N + rin0) = o;
    }
}

// ------- m97-style aggregation: msgp[ksp] = x[b](rows, Krange) @ m[b] ------------------
// 128x128 C-tile, BK=64, global_load_lds staging, 4 waves each own a 64x64 quadrant.
__global__ __launch_bounds__(256)
void agg_mfma_kernel(const unsigned short* __restrict__ xb,
                     const unsigned short* __restrict__ mt,
                     float* __restrict__ msgp, int N, long long BNH)
{
    __shared__ short sA[128 * 64];   // x tile: 128 rows x 64 k (bf16), row-major, no pad
    __shared__ short sB[128 * 64];   // m_t tile: 128 H-rows x 64 k

    const int tid = threadIdx.x;
    const int lane = tid & 63, w = tid >> 6;
    const int lr = lane & 15, lq = lane >> 4;
    const int wr = w & 1, wc = w >> 1;
    const int r0 = blockIdx.x * 128;
    const int ksp = blockIdx.y;
    const int batch = blockIdx.z;
    const int kbase = ksp * (N >> 2);
    const int nsteps = (N >> 2) >> 6;

    const unsigned short* xrow = xb + (long long)batch * N * N;
    const unsigned short* mrow = mt + (long long)batch * 128 * N;

    f32x4 acc[4][4];
#pragma unroll
    for (int tr = 0; tr < 4; ++tr)
#pragma unroll
        for (int tn = 0; tn < 4; ++tn) acc[tr][tn] = (f32x4)(0.f);

    for (int step = 0; step < nsteps; ++step) {
        const int k0 = kbase + step * 64;
        // stage sA (16 KB = 1024 chunks of 16B): 4 insts/wave, 64 lanes each
#pragma unroll
        for (int j = 0; j < 4; ++j) {
            const int c = ((w * 4 + j) << 6) + lane;       // chunk index
            const unsigned short* g = xrow + (long long)(r0 + (c >> 3)) * N + k0 + (c & 7) * 8;
            gload_lds16(g, (char*)sA + (w * 4 + j) * 1024);
        }
        // stage sB (16 KB)
#pragma unroll
        for (int j = 0; j < 4; ++j) {
            const int c = ((w * 4 + j) << 6) + lane;
            const unsigned short* g = mrow + (long long)(c >> 3) * N + k0 + (c & 7) * 8;
            gload_lds16(g, (char*)sB + (w * 4 + j) * 1024);
        }
        __syncthreads();     // compiler drains vmcnt before s_barrier
#pragma unroll
        for (int ks = 0; ks < 2; ++ks) {
            bf16x8 af[4], bfr[4];
#pragma unroll
            for (int tr = 0; tr < 4; ++tr)
                af[tr] = *(const bf16x8*)((const char*)sA + (wr * 64 + tr * 16 + lr) * 128 + ks * 64 + lq * 16);
#pragma unroll
            for (int tn = 0; tn < 4; ++tn)
                bfr[tn] = *(const bf16x8*)((const char*)sB + (wc * 64 + tn * 16 + lr) * 128 + ks * 64 + lq * 16);
#pragma unroll
            for (int tr = 0; tr < 4; ++tr)
#pragma unroll
                for (int tn = 0; tn < 4; ++tn)
                    acc[tr][tn] = __builtin_amdgcn_mfma_f32_16x16x32_bf16(af[tr], bfr[tn], acc[tr][tn], 0, 0, 0);
        }
        __syncthreads();
    }

    float* outb = msgp + (long long)ksp * BNH + (long long)(batch * N + r0) * 128;
#pragma unroll
    for (int tr = 0; tr < 4; ++tr)
#pragma unroll
        for (int tn = 0; tn < 4; ++tn)
#pragma unroll
            for (int r = 0; r < 4; ++r)
                outb[(long long)(wr * 64 + tr * 16 + lq * 4 + r) * 128 + wc * 64 + tn * 16 + lr] = acc[tr][tn][r];
}

// ---------------- fallback aggregation (fp32 x), writes fp32 into msgp[0] -------------
__global__ __launch_bounds__(256)
void agg_fallback_kernel(const float* __restrict__ xf,
                         const unsigned short* __restrict__ mt, float* __restrict__ msgp0,
                         int N)
{
    __shared__ float sacc[4][16][132];
    const int lane = threadIdx.x & 63, wave = threadIdx.x >> 6;
    const int lr = lane & 15, lq = lane >> 4;
    const int batch = blockIdx.y;
    const int rowBase = blockIdx.x * 16;
    const int kBase = wave * (N >> 2);
    const int kIters = N >> 7;

    const float* af = xf + (long long)batch * N * N + (long long)(rowBase + lr) * N + kBase + lq * 8;
    const long long bbase = (long long)batch * 128 * N + (long long)lr * N + kBase + lq * 8;

    f32x4 acc[8];
#pragma unroll
    for (int tn = 0; tn < 8; ++tn) acc[tn] = (f32x4)(0.f);

    for (int it = 0; it < kIters; ++it) {
        const int k = it * 32;
        float4 lo = *(const float4*)(af + k);
        float4 hi = *(const float4*)(af + k + 4);
        bf16x8 a0;
        a0[0] = (short)f2bf(lo.x); a0[1] = (short)f2bf(lo.y);
        a0[2] = (short)f2bf(lo.z); a0[3] = (short)f2bf(lo.w);
        a0[4] = (short)f2bf(hi.x); a0[5] = (short)f2bf(hi.y);
        a0[6] = (short)f2bf(hi.z); a0[7] = (short)f2bf(hi.w);
#pragma unroll
        for (int tn = 0; tn < 8; ++tn) {
            bf16x8 b0 = *(const bf16x8*)(mt + bbase + (long long)tn * 16 * N + k);
            acc[tn] = __builtin_amdgcn_mfma_f32_16x16x32_bf16(a0, b0, acc[tn], 0, 0, 0);
        }
    }

#pragma unroll
    for (int tn = 0; tn < 8; ++tn)
#pragma unroll
        for (int r = 0; r < 4; ++r)
            sacc[wave][lq * 4 + r][tn * 16 + lr] = acc[tn][r];
    __syncthreads();
    {
        const int t = threadIdx.x;
        const int row = t >> 4, cb2 = (t & 15) * 8;
        float o[8];
#pragma unroll
        for (int j = 0; j < 8; ++j)
            o[j] = sacc[0][row][cb2 + j] + sacc[1][row][cb2 + j]
                 + sacc[2][row][cb2 + j] + sacc[3][row][cb2 + j];
        float* dst = msgp0 + (long long)(batch * N + rowBase + row) * 128 + cb2;
        *(float4*)dst = make_float4(o[0], o[1], o[2], o[3]);
        *(float4*)(dst + 4) = make_float4(o[4], o[5], o[6], o[7]);
    }
}

// ------- fused dual-GEMM gates + LSTM + LayerNorm; cols split across waves -------------
template<int NPART>
__global__ __launch_bounds__(256)
void gates_lstm_kernel(const float* __restrict__ msgp, long long BNH,
                       unsigned short* hb, float* cb,
                       const unsigned short* __restrict__ wih,
                       const unsigned short* __restrict__ whh,
                       const float* __restrict__ bih, const float* __restrict__ bhh,
                       const float* __restrict__ lng, const float* __restrict__ lnb,
                       unsigned short* __restrict__ embed_out)
{
    __shared__ float sred[4][16][2];
    const int lane = threadIdx.x & 63, wave = threadIdx.x >> 6;
    const int lr = lane & 15, lq = lane >> 4;
    const int r0 = blockIdx.x * 16;

    f32x4 acc[8];    // tt = gate*2 + half
#pragma unroll
    for (int t = 0; t < 8; ++t) acc[t] = (f32x4)(0.f);

    // A-fragments from the summed fp32 partials, converted to bf16
    bf16x8 a[4];
#pragma unroll
    for (int s = 0; s < 4; ++s) {
        const long long base = (long long)(r0 + lr) * 128 + s * 32 + lq * 8;
        float v[8];
        {
            float4 t0 = *(const float4*)(msgp + base);
            float4 t1 = *(const float4*)(msgp + base + 4);
            v[0] = t0.x; v[1] = t0.y; v[2] = t0.z; v[3] = t0.w;
            v[4] = t1.x; v[5] = t1.y; v[6] = t1.z; v[7] = t1.w;
        }
#pragma unroll
        for (int j = 1; j < NPART; ++j) {
            float4 t0 = *(const float4*)(msgp + j * BNH + base);
            float4 t1 = *(const float4*)(msgp + j * BNH + base + 4);
            v[0] += t0.x; v[1] += t0.y; v[2] += t0.z; v[3] += t0.w;
            v[4] += t1.x; v[5] += t1.y; v[6] += t1.z; v[7] += t1.w;
        }
        bf16x8 r8;
#pragma unroll
        for (int e = 0; e < 8; ++e) r8[e] = (short)f2bf(v[e]);
        a[s] = r8;
    }
#pragma unroll
    for (int s = 0; s < 4; ++s)
#pragma unroll
        for (int tt = 0; tt < 8; ++tt) {
            const int brow = (tt >> 1) * 128 + wave * 32 + (tt & 1) * 16 + lr;
            bf16x8 b = *(const bf16x8*)(wih + brow * 128 + s * 32 + lq * 8);
            acc[tt] = __builtin_amdgcn_mfma_f32_16x16x32_bf16(a[s], b, acc[tt], 0, 0, 0);
        }
#pragma unroll
    for (int s = 0; s < 4; ++s)
        a[s] = *(const bf16x8*)((const unsigned short*)hb + (long long)(r0 + lr) * 128 + s * 32 + lq * 8);
#pragma unroll
    for (int s = 0; s < 4; ++s)
#pragma unroll
        for (int tt = 0; tt < 8; ++tt) {
            const int brow = (tt >> 1) * 128 + wave * 32 + (tt & 1) * 16 + lr;
            bf16x8 b = *(const bf16x8*)(whh + brow * 128 + s * 32 + lq * 8);
            acc[tt] = __builtin_amdgcn_mfma_f32_16x16x32_bf16(a[s], b, acc[tt], 0, 0, 0);
        }

    float hn[2][4];
    float4* cw = (float4*)cb;
#pragma unroll
    for (int half = 0; half < 2; ++half) {
        const int col = wave * 32 + half * 16 + lr;
        const float bi  = bih[col]       + bhh[col];
        const float bf_ = bih[col + 128] + bhh[col + 128];
        const float bg  = bih[col + 256] + bhh[col + 256];
        const float bo  = bih[col + 384] + bhh[col + 384];
        const long long cidx = ((long long)blockIdx.x * 8 + wave * 2 + half) * 64 + lane;
        float4 cold = cw[cidx];
        float co[4] = {cold.x, cold.y, cold.z, cold.w};
        float cn[4];
#pragma unroll
        for (int r = 0; r < 4; ++r) {
            float iv = acc[0 + half][r] + bi;
            float fv = acc[2 + half][r] + bf_;
            float gv = acc[4 + half][r] + bg;
            float ov = acc[6 + half][r] + bo;
            float cc = sigf(fv) * co[r] + sigf(iv) * tanhf(gv);
            cn[r] = cc;
            hn[half][r] = sigf(ov) * tanhf(cc);
        }
        float4 cnew = {cn[0], cn[1], cn[2], cn[3]};
        cw[cidx] = cnew;
    }

    float ps1[4], ps2[4];
#pragma unroll
    for (int r = 0; r < 4; ++r) {
        float s1 = hn[0][r] + hn[1][r];
        float s2 = hn[0][r] * hn[0][r] + hn[1][r] * hn[1][r];
#pragma unroll
        for (int m = 1; m <= 8; m <<= 1) {
            s1 += __shfl_xor(s1, m);
            s2 += __shfl_xor(s2, m);
        }
        ps1[r] = s1; ps2[r] = s2;
    }
    if (lr == 0) {
#pragma unroll
        for (int r = 0; r < 4; ++r) {
            sred[wave][lq * 4 + r][0] = ps1[r];
            sred[wave][lq * 4 + r][1] = ps2[r];
        }
    }
    __syncthreads();

#pragma unroll
    for (int half = 0; half < 2; ++half) {
        const int col = wave * 32 + half * 16 + lr;
        const float g = lng[col], bb = lnb[col];
#pragma unroll
        for (int r = 0; r < 4; ++r) {
            const int row = lq * 4 + r;
            float S1 = sred[0][row][0] + sred[1][row][0] + sred[2][row][0] + sred[3][row][0];
            float S2 = sred[0][row][1] + sred[1][row][1] + sred[2][row][1] + sred[3][row][1];
            float mean = S1 * (1.f / 128.f);
            float var  = S2 * (1.f / 128.f) - mean * mean;
            float rs = rsqrtf(var + LN_EPS);
            long long off = (long long)(r0 + row) * 128 + col;
            hb[off] = f2bf(hn[half][r]);
            embed_out[off] = f2bf((hn[half][r] - mean) * rs * g + bb);
        }
    }
}

// ---------------- fused vote MLP (2 layers) + layer3 dot + masked sum ------------------
__global__ __launch_bounds__(256)
void vote_mlp_kernel(const unsigned short* __restrict__ embed,
                     const unsigned short* __restrict__ w1, const float* __restrict__ b1,
                     const unsigned short* __restrict__ w2, const float* __restrict__ b2,
                     const float* __restrict__ w3, const float* __restrict__ b3p,
                     const float* __restrict__ mask, float* __restrict__ logit, int N)
{
    __shared__ unsigned short sact[4][16][136];
    const int lane = threadIdx.x & 63, wave = threadIdx.x >> 6;
    const int lr = lane & 15, lq = lane >> 4;
    const int r0 = (blockIdx.x * 4 + wave) * 16;

    bf16x8 a[4];
    f32x4 acc[8];
#pragma unroll
    for (int s = 0; s < 4; ++s)
        a[s] = *(const bf16x8*)(embed + (long long)(r0 + lr) * 128 + s * 32 + lq * 8);
#pragma unroll
    for (int tn = 0; tn < 8; ++tn) acc[tn] = (f32x4)(0.f);
    layer128(w1, a, acc, lr, lq);

#pragma unroll
    for (int tn = 0; tn < 8; ++tn) {
        float bb = b1[tn * 16 + lr];
#pragma unroll
        for (int r = 0; r < 4; ++r) {
            float v = acc[tn][r] + bb; v = v > 0.f ? v : 0.f;
            sact[wave][lq * 4 + r][tn * 16 + lr] = f2bf(v);
        }
    }
    __syncthreads();
#pragma unroll
    for (int s = 0; s < 4; ++s)
        a[s] = *(const bf16x8*)&sact[wave][lr][s * 32 + lq * 8];
#pragma unroll
    for (int tn = 0; tn < 8; ++tn) acc[tn] = (f32x4)(0.f);
    layer128(w2, a, acc, lr, lq);

    float dot[4] = {0.f, 0.f, 0.f, 0.f};
#pragma unroll
    for (int tn = 0; tn < 8; ++tn) {
        const int col = tn * 16 + lr;
        const float bb = b2[col], w3c = w3[col];
#pragma unroll
        for (int r = 0; r < 4; ++r) {
            float v = acc[tn][r] + bb; v = v > 0.f ? v : 0.f;
            dot[r] += v * w3c;
        }
    }
#pragma unroll
    for (int r = 0; r < 4; ++r)
#pragma unroll
        for (int m = 1; m <= 8; m <<= 1) dot[r] += __shfl_xor(dot[r], m);

    const int batch = r0 / N;
    const float b3 = b3p[0];
    const int base = r0 + lq * 4;
    float wsum = mask[base + 0] * (dot[0] + b3) + mask[base + 1] * (dot[1] + b3)
               + mask[base + 2] * (dot[2] + b3) + mask[base + 3] * (dot[3] + b3);
    float t = (lr == 0) ? wsum : 0.f;
    t += __shfl_xor(t, 16);
    t += __shfl_xor(t, 32);
    if (lane == 0) atomicAdd(&logit[batch], t);
}

// ---------------- small kernels --------------------------------------------------------
__global__ __launch_bounds__(128)
void init_kernel(const float* __restrict__ kk, const float* __restrict__ nn,
                 const float* __restrict__ w1, const float* __restrict__ b1,
                 const float* __restrict__ w2, const float* __restrict__ b2,
                 const float* __restrict__ w3, const float* __restrict__ b3,
                 const float* __restrict__ lng, const float* __restrict__ lnb,
                 float* __restrict__ init0, float* __restrict__ embed0,
                 float* __restrict__ logit, int H)
{
    int b = blockIdx.x, j = threadIdx.x;
    __shared__ float s1[128];
    __shared__ float s2[128];
    __shared__ float red[128];
    if (j == 0) logit[b] = 0.f;
    float kv = kk[b], nv = nn[b];
    float h1 = w1[j * 2 + 0] * kv + w1[j * 2 + 1] * nv + b1[j];
    h1 = h1 > 0.f ? h1 : 0.f;
    s1[j] = h1; __syncthreads();
    float h2 = b2[j];
    for (int q = 0; q < H; ++q) h2 += w2[j * H + q] * s1[q];
    h2 = h2 > 0.f ? h2 : 0.f;
    s2[j] = h2; __syncthreads();
    float o = b3[j];
    for (int q = 0; q < H; ++q) o += w3[j * H + q] * s2[q];
    init0[b * H + j] = o;

    red[j] = o; __syncthreads();
    for (int s = 64; s > 0; s >>= 1) { if (j < s) red[j] += red[j + s]; __syncthreads(); }
    float mu = red[0] / (float)H;
    __syncthreads();
    float d = o - mu;
    red[j] = d * d; __syncthreads();
    for (int s = 64; s > 0; s >>= 1) { if (j < s) red[j] += red[j + s]; __syncthreads(); }
    float var = red[0] / (float)H;
    embed0[b * H + j] = d * rsqrtf(var + LN_EPS) * lng[j] + lnb[j];
}

__global__ void bcast_kernel(const float* __restrict__ init0, const float* __restrict__ embed0,
                             unsigned short* __restrict__ hb, float* __restrict__ cb,
                             unsigned short* __restrict__ embed,
                             long long total, long long NH)
{
    long long idx = (long long)blockIdx.x * blockDim.x + threadIdx.x;
    if (idx >= total) return;
    int b = (int)(idx / NH);
    int j = (int)(idx & 127);
    hb[idx] = f2bf(init0[b * 128 + j]);
    embed[idx] = f2bf(embed0[b * 128 + j]);
    cb[idx] = 0.f;
}

__global__ void cast_kernel(const float* __restrict__ x, unsigned short* __restrict__ xb,
                            long long n4)
{
    long long i = ((long long)blockIdx.x * blockDim.x + threadIdx.x);
    if (i >= n4) return;
    float4 v = *(const float4*)(x + i * 4);
    ushort4 o;
    o.x = f2bf(v.x); o.y = f2bf(v.y); o.z = f2bf(v.z); o.w = f2bf(v.w);
    *(ushort4*)&xb[i * 4] = o;
}

struct CastArgs {
    const float* src[7];
    unsigned short* dst[7];
    int n[7];
};

__global__ void castw_kernel(CastArgs a)
{
    int rg = blockIdx.y;
    int i = (blockIdx.x * blockDim.x + threadIdx.x) * 4;
    if (i < a.n[rg]) {
        float4 v = *(const float4*)(a.src[rg] + i);
        ushort4 o;
        o.x = f2bf(v.x); o.y = f2bf(v.y); o.z = f2bf(v.z); o.w = f2bf(v.w);
        *(ushort4*)(a.dst[rg] + i) = o;
    }
}

__global__ void sigmoid_kernel(const float* __restrict__ logit, float* __restrict__ out, int B)
{
    int b = threadIdx.x;
    if (b < B) out[b] = 1.f / (1.f + __expf(-logit[b]));
}

// ---------------- launch ---------------------------------------------------------------
extern "C" void kernel_launch(void* const* d_in, const int* in_sizes, int n_in,
                              void* d_out, int out_size, void* d_ws, size_t ws_size,
                              hipStream_t stream)
{
    const float* x    = (const float*)d_in[0];
    const float* kk   = (const float*)d_in[1];
    const float* nn   = (const float*)d_in[2];
    const float* mask = (const float*)d_in[3];
    const float* iw1  = (const float*)d_in[4];
    const float* ib1  = (const float*)d_in[5];
    const float* iw2  = (const float*)d_in[6];
    const float* ib2  = (const float*)d_in[7];
    const float* iw3  = (const float*)d_in[8];
    const float* ib3  = (const float*)d_in[9];
    const float* mw1  = (const float*)d_in[10];
    const float* mb1  = (const float*)d_in[11];
    const float* mw2  = (const float*)d_in[12];
    const float* mb2  = (const float*)d_in[13];
    const float* mw3  = (const float*)d_in[14];
    const float* mb3  = (const float*)d_in[15];
    const float* wih  = (const float*)d_in[16];
    const float* whh  = (const float*)d_in[17];
    const float* bih  = (const float*)d_in[18];
    const float* bhh  = (const float*)d_in[19];
    const float* lng  = (const float*)d_in[20];
    const float* lnb  = (const float*)d_in[21];
    const float* vw1  = (const float*)d_in[22];
    const float* vb1  = (const float*)d_in[23];
    const float* vw2  = (const float*)d_in[24];
    const float* vb2  = (const float*)d_in[25];
    const float* vw3  = (const float*)d_in[26];
    const float* vb3  = (const float*)d_in[27];
    float* out = (float*)d_out;

    const int B = in_sizes[1];        // 4
    const int H = in_sizes[5];        // 128
    const int N = in_sizes[3] / B;    // 4096
    const long long NH  = (long long)N * H;
    const long long BNH = (long long)B * NH;
    const int M = B * N;

    char* p = (char*)d_ws;
    auto alloc = [&](long long bytes) {
        char* q = p; p += (bytes + 255) & ~255LL; return q;
    };
    float*          cb     = (float*)alloc(BNH * 4);
    unsigned short* embed  = (unsigned short*)alloc(BNH * 2);
    unsigned short* hb     = (unsigned short*)alloc(BNH * 2);
    unsigned short* m_t    = (unsigned short*)alloc(BNH * 2);
    float*          msgp   = (float*)alloc(4 * BNH * 4);      // 4 fp32 K-split partials
    float*          init0  = (float*)alloc((long long)B * H * 4);
    float*          embed0 = (float*)alloc((long long)B * H * 4);
    float*          logit  = (float*)alloc((long long)B * 4);
    unsigned short* wb_m1  = (unsigned short*)alloc((long long)H * H * 2);
    unsigned short* wb_m2  = (unsigned short*)alloc((long long)H * H * 2);
    unsigned short* wb_m3  = (unsigned short*)alloc((long long)H * H * 2);
    unsigned short* wb_ih  = (unsigned short*)alloc(4LL * H * H * 2);
    unsigned short* wb_hh  = (unsigned short*)alloc(4LL * H * H * 2);
    unsigned short* wb_v1  = (unsigned short*)alloc((long long)H * H * 2);
    unsigned short* wb_v2  = (unsigned short*)alloc((long long)H * H * 2);
    unsigned short* x_bf   = (unsigned short*)alloc(2LL * B * N * N);
    const bool use_xb = ((long long)(p - (char*)d_ws) <= (long long)ws_size);

    init_kernel<<<B, H, 0, stream>>>(kk, nn, iw1, ib1, iw2, ib2, iw3, ib3, lng, lnb,
                                     init0, embed0, logit, H);
    {
        long long nb = (BNH + 255) / 256;
        bcast_kernel<<<dim3((unsigned)nb), 256, 0, stream>>>(init0, embed0, hb, cb, embed, BNH, NH);
    }
    {
        CastArgs ca;
        ca.src[0] = mw1; ca.dst[0] = wb_m1; ca.n[0] = H * H;
        ca.src[1] = mw2; ca.dst[1] = wb_m2; ca.n[1] = H * H;
        ca.src[2] = mw3; ca.dst[2] = wb_m3; ca.n[2] = H * H;
        ca.src[3] = wih; ca.dst[3] = wb_ih; ca.n[3] = 4 * H * H;
        ca.src[4] = whh; ca.dst[4] = wb_hh; ca.n[4] = 4 * H * H;
        ca.src[5] = vw1; ca.dst[5] = wb_v1; ca.n[5] = H * H;
        ca.src[6] = vw2; ca.dst[6] = wb_v2; ca.n[6] = H * H;
        castw_kernel<<<dim3(64, 7), 256, 0, stream>>>(ca);
    }
    if (use_xb) {
        long long n4 = (long long)B * N * N / 4;
        cast_kernel<<<dim3((unsigned)((n4 + 255) / 256)), 256, 0, stream>>>(x, x_bf, n4);
    }

    dim3 gridRow(M / 64);
    dim3 gridRow16(M / 16);
    dim3 gridAggNew(N / 128, 4, B);     // rowtiles x ksplit x batch = 512 blocks
    dim3 gridAggOld(N / 16, B);

    for (int it = 0; it < 8; ++it) {
        msg_mlp_kernel<<<gridRow, 256, 0, stream>>>(embed, wb_m1, mb1, wb_m2, mb2,
                                                    wb_m3, mb3, m_t, N);
        if (use_xb) {
            agg_mfma_kernel<<<gridAggNew, 256, 0, stream>>>(x_bf, m_t, msgp, N, BNH);
            gates_lstm_kernel<4><<<gridRow16, 256, 0, stream>>>(msgp, BNH, hb, cb, wb_ih, wb_hh,
                                                                bih, bhh, lng, lnb, embed);
        } else {
            agg_fallback_kernel<<<gridAggOld, 256, 0, stream>>>(x, m_t, msgp, N);
            gates_lstm_kernel<1><<<gridRow16, 256, 0, stream>>>(msgp, BNH, hb, cb, wb_ih, wb_hh,
                                                                bih, bhh, lng, lnb, embed);
        }
    }

    vote_mlp_kernel<<<gridRow, 256, 0, stream>>>(embed, wb_v1, vb1, wb_v2, vb2,
                                                 vw3, vb3, mask, logit, N);
    sigmoid_kernel<<<1, 64, 0, stream>>>(logit, out, B);
}